// Round 12
// baseline (189.060 us; speedup 1.0000x reference)
//
#include <hip/hip_runtime.h>

#define B_ 32
#define C_ 256
#define D_ 128
#define HH 56
#define WW 56
#define N_ 3136
#define KSPLIT 7
#define KRANGE 448   // n per K-split in k2: 14 steps of 32

typedef float f32x4 __attribute__((ext_vector_type(4)));
typedef short s16x8 __attribute__((ext_vector_type(8)));
typedef unsigned short u16x8 __attribute__((ext_vector_type(8)));

// Row swizzle for [R][32-bf16] LDS tiles (64B rows = 4x16B units).
__device__ __forceinline__ int swz4(int r){
  return (r & 3) ^ (((r >> 2) & 1) << 1) ^ ((r >> 3) & 1);
}
__device__ __forceinline__ unsigned short f2bf(float f){
  unsigned u = __float_as_uint(f);
  u += 0x7fffu + ((u >> 16) & 1u);           // RNE
  return (unsigned short)(u >> 16);
}
__device__ __forceinline__ float bf2f(unsigned short h){
  return __uint_as_float(((unsigned)h) << 16);
}
__device__ __forceinline__ float elu1(float v){
  return v > 0.f ? v + 1.f : __expf(v);      // elu(v)+1
}
// HW packed f32x2 -> bf16x2 (RNE), 1 instr for 2 values.
__device__ __forceinline__ unsigned cvtpk(float lo, float hi){
  unsigned r;
  asm("v_cvt_pk_bf16_f32 %0, %1, %2" : "=v"(r) : "v"(lo), "v"(hi));
  return r;
}

// Stage [R rows][32 bf16] from bf16 global (pitch ld) into swizzled LDS via
// global_load_lds: dest is lane-linear, swizzle pre-applied on global source.
// 256-thread variant.
template<int R>
__device__ __forceinline__ void stage_glds(const unsigned short* gp, int ld, char* lds){
  const int tid = threadIdx.x;
  const int wid = tid >> 6;
#pragma unroll
  for (int q = 0; q < R/64; ++q){
    const int slot = q*256 + tid;            // = r*4 + unit
    const int r = slot >> 2, gi = slot & 3;
    const int u = gi ^ swz4(r);
    const unsigned short* ga = gp + r*ld + u*8;
    char* lb = lds + (q*256 + wid*64)*16;    // wave-uniform LDS base
    __builtin_amdgcn_global_load_lds(
        (__attribute__((address_space(1))) void*)ga,
        (__attribute__((address_space(3))) void*)lb, 16, 0, 0);
  }
}

__device__ __forceinline__ s16x8 ldsfrag(const char* lds, int r, int g){
  return *(const s16x8*)(lds + r*64 + ((g ^ swz4(r)) << 4));
}

// ---------------------------------------------------------------------------
// K0w: W fp32 -> bf16.
// ---------------------------------------------------------------------------
__global__ __launch_bounds__(256) void k0_w(
    const float* __restrict__ w, unsigned short* __restrict__ wb)
{
  const int i = blockIdx.x*256 + threadIdx.x;   // 16384 float4s
  float4 v = *(const float4*)(w + (size_t)i*4);
  uint2 h = {cvtpk(v.x, v.y), cvtpk(v.z, v.w)};
  *(uint2*)(wb + (size_t)i*4) = h;
}

// ---------------------------------------------------------------------------
// K0t v3: xt[b][n][c] = transpose(x[b][c][n]) bf16; M=1 also xb16[b][c][n].
// WAVE-PRIVATE, BARRIER-FREE (r11 lesson: grid collapse killed TLP; r10
// lesson: block-wide barrier convoy + latency). Each wave owns a 32c x 64n
// sub-tile in its own LDS region (packed bf16x2, cvt done once in regs and
// reused for xb16), transpose-reads only its own writes -> lgkmcnt-ordered,
// no __syncthreads. Grid (49,2,32)=3136 blocks keeps TLP high.
// ---------------------------------------------------------------------------
template<int M>
__global__ __launch_bounds__(256) void k0_t(
    const float* __restrict__ x, unsigned short* __restrict__ xt,
    unsigned short* __restrict__ xb16)
{
  __shared__ unsigned Tp[4][32][33];   // [wave][c'][n-pair], pitch 33 (2-way max)
  const int tid = threadIdx.x, lane = tid & 63, w = tid >> 6;
  const int n0 = blockIdx.x*64, b = blockIdx.z;
  const int c0w = blockIdx.y*128 + w*32;       // wave's 32-channel range
  const int r = lane >> 1, q = lane & 1;       // c'-row, n-half (32 each)
  const int c = c0w + r;

  // phase 1: load 32 fp32 (128B contiguous), cvt once, feed xb16 + LDS
  const float4* xp = (const float4*)(x + ((size_t)b*C_ + c)*N_ + n0 + q*32);
  float4 v[8];
#pragma unroll
  for (int t = 0; t < 8; ++t) v[t] = xp[t];
  unsigned h[16];
#pragma unroll
  for (int t = 0; t < 8; ++t){
    h[2*t]   = cvtpk(v[t].x, v[t].y);
    h[2*t+1] = cvtpk(v[t].z, v[t].w);
  }
  if (M){
    uint4* dst = (uint4*)(xb16 + ((size_t)b*C_ + c)*N_ + n0 + q*32);
#pragma unroll
    for (int t = 0; t < 4; ++t)
      dst[t] = (uint4){h[4*t], h[4*t+1], h[4*t+2], h[4*t+3]};
  }
#pragma unroll
  for (int j = 0; j < 16; ++j)
    Tp[w][r][q*16 + j] = h[j];                 // banks (r+16q+j)%32: 2-way, free

  // phase 2 (same wave, lgkmcnt-ordered): lane l emits xt row n = n0+l for
  // the wave's 32 channels. T col = n-pair (l>>1), half = l&1.
  const int half = q;                          // = l&1 via (lane&1)? no: recompute
  const int np = lane >> 1, hs = (lane & 1)*16;
  unsigned t32[32];
#pragma unroll
  for (int cc = 0; cc < 32; ++cc) t32[cc] = Tp[w][cc][np];   // 2-lane broadcast
  (void)half;
  unsigned o[16];
#pragma unroll
  for (int j = 0; j < 16; ++j){
    const unsigned lo = (t32[2*j]   >> hs) & 0xffffu;
    const unsigned hi = (t32[2*j+1] >> hs) & 0xffffu;
    o[j] = lo | (hi << 16);
  }
  uint4* od = (uint4*)(xt + ((size_t)b*N_ + n0 + lane)*C_ + c0w);
#pragma unroll
  for (int j = 0; j < 4; ++j)
    od[j] = (uint4){o[4*j], o[4*j+1], o[4*j+2], o[4*j+3]};
}

// ---------------------------------------------------------------------------
// K1: qk = elu(W.x + b)+1.  MFMA GEMM M=256(o) x BN=64(n) x K=256(c).
// Pure global_load_lds staging. Waves 0-1 -> q half stored qt[b][n][d];
// waves 2-3 -> k half kbuf[b][d][n].  (EXACT round-7 version — proven.)
// ---------------------------------------------------------------------------
__global__ __launch_bounds__(256) void k1_qk(
    const unsigned short* __restrict__ xt, const unsigned short* __restrict__ wb,
    const float* __restrict__ bias,
    unsigned short* __restrict__ kbuf, unsigned short* __restrict__ qt)
{
  __shared__ __align__(16) char Al[256*64];  // [256 o][32 c] bf16, swizzled
  __shared__ __align__(16) char Bl[64*64];   // [64 n][32 c]  bf16, swizzled
  const int tid = threadIdx.x, lane = tid & 63, wid = tid >> 6;
  const int n0 = blockIdx.x * 64;
  const int b  = blockIdx.y;
  const unsigned short* xtb = xt + ((size_t)b*N_ + n0)*C_;
  const int wo = wid*64;
  f32x4 acc[4][4] = {};

  for (int k0 = 0; k0 < C_; k0 += 32){
    __syncthreads();
    stage_glds<256>(wb + k0, C_, Al);
    stage_glds<64>(xtb + k0, C_, Bl);
    __syncthreads();
    s16x8 af[4], bv4[4];
#pragma unroll
    for (int m = 0; m < 4; ++m)  af[m]  = ldsfrag(Al, wo + m*16 + (lane & 15), lane >> 4);
#pragma unroll
    for (int nf = 0; nf < 4; ++nf) bv4[nf] = ldsfrag(Bl, nf*16 + (lane & 15), lane >> 4);
#pragma unroll
    for (int m = 0; m < 4; ++m)
#pragma unroll
      for (int nf = 0; nf < 4; ++nf)
        acc[m][nf] = __builtin_amdgcn_mfma_f32_16x16x32_bf16(af[m], bv4[nf], acc[m][nf], 0, 0, 0);
  }

  const int col = lane & 15, rg = lane >> 4;
  if (wid < 2){
    // q half -> qt[b][n][d]
#pragma unroll
    for (int m = 0; m < 4; ++m){
      const int db = wo + m*16 + rg*4;
      const float b0 = bias[db], b1 = bias[db+1], b2 = bias[db+2], b3 = bias[db+3];
#pragma unroll
      for (int nf = 0; nf < 4; ++nf){
        const int n = n0 + nf*16 + col;
        f32x4 a = acc[m][nf];
        uint2 hv = {cvtpk(elu1(a[0]+b0), elu1(a[1]+b1)),
                    cvtpk(elu1(a[2]+b2), elu1(a[3]+b3))};
        *(uint2*)(qt + ((size_t)b*N_ + n)*D_ + db) = hv;
      }
    }
  } else {
    // k half -> kbuf[b][d][n]
#pragma unroll
    for (int m = 0; m < 4; ++m)
#pragma unroll
      for (int j = 0; j < 4; ++j){
        const int d = wo - 128 + m*16 + rg*4 + j;
        const float bb = bias[128 + d];
#pragma unroll
        for (int nf = 0; nf < 4; ++nf){
          const int n = n0 + nf*16 + col;
          kbuf[((size_t)b*D_ + d)*N_ + n] = f2bf(elu1(acc[m][nf][j] + bb));
        }
      }
  }
}

// ---------------------------------------------------------------------------
// K2: kv partials = sum_n k[d][n]*x[c][n] over K-split. M=128(d) x BN=256(c)
// x K=448(n). 512 threads / 8 waves. Partials stored [c][d]. Fuses kmean.
// M=0: B from x fp32 + cvt_pk (r7 proven). M=1: B pure DMA from xb16.
// (EXACT round-10 version — proven.)
// ---------------------------------------------------------------------------
template<int M>
__global__ __launch_bounds__(512) void k2_kv(
    const unsigned short* __restrict__ kbuf, const float* __restrict__ x,
    const unsigned short* __restrict__ xb16,
    unsigned short* __restrict__ kvp, float* __restrict__ kmp)
{
  __shared__ __align__(16) char Al[128*64];  // [128 d][32 n]
  __shared__ __align__(16) char Bl[256*64];  // [256 c][32 n]
  const int tid = threadIdx.x, lane = tid & 63, wid = tid >> 6;  // 8 waves
  const int ks = blockIdx.x;
  const int b  = blockIdx.y;
  const unsigned short* kb = kbuf + (size_t)b*D_*N_ + ks*KRANGE;
  const float* xb = x + (size_t)b*C_*N_ + ks*KRANGE;
  const unsigned short* xbb = xb16 + (size_t)b*C_*N_ + ks*KRANGE;
  const int wd = (wid >> 2)*64, wc = (wid & 3)*64;
  f32x4 acc[4][4] = {};
  float kms = 0.f;
  const int sr = tid >> 2, sg = tid & 3;     // staging/kms row & unit

  for (int t = 0; t < KRANGE/32; ++t){
    __syncthreads();
    // A: 128 rows x 4 units = 512 slots, one global_load_lds per thread
    {
      const int u = sg ^ swz4(sr);
      const unsigned short* ga = kb + (size_t)sr*N_ + t*32 + u*8;
      char* lb = Al + (wid*64)*16;           // wave-uniform base; unit = tid
      __builtin_amdgcn_global_load_lds(
          (__attribute__((address_space(1))) void*)ga,
          (__attribute__((address_space(3))) void*)lb, 16, 0, 0);
    }
    if (M){
      // B: 256 rows x 4 units = 1024 slots, two DMAs per thread
#pragma unroll
      for (int q = 0; q < 2; ++q){
        const int slot = q*512 + tid;
        const int r = slot >> 2, gi = slot & 3;
        const int u = gi ^ swz4(r);
        const unsigned short* ga = xbb + (size_t)r*N_ + t*32 + u*8;
        char* lb = Bl + (q*512 + wid*64)*16;
        __builtin_amdgcn_global_load_lds(
            (__attribute__((address_space(1))) void*)ga,
            (__attribute__((address_space(3))) void*)lb, 16, 0, 0);
      }
    } else {
      // B: x[c][n] fp32 -> bf16 (cvt_pk); 256 rows x 32 n, 16 elems/thread
#pragma unroll
      for (int q = 0; q < 4; ++q){
        int idx = q*512 + tid;                 // 0..2047
        int cc = idx >> 3, n4 = (idx & 7)*4;
        float4 v = *(const float4*)(xb + (size_t)cc*N_ + t*32 + n4);
        uint2 h = {cvtpk(v.x, v.y), cvtpk(v.z, v.w)};
        *(uint2*)(Bl + cc*64 + ((n4*2) ^ (swz4(cc) << 4))) = h;
      }
    }
    __syncthreads();
    s16x8 af[4], bv[4];
#pragma unroll
    for (int m = 0; m < 4; ++m)  af[m] = ldsfrag(Al, wd + m*16 + (lane & 15), lane >> 4);
#pragma unroll
    for (int cf = 0; cf < 4; ++cf) bv[cf] = ldsfrag(Bl, wc + cf*16 + (lane & 15), lane >> 4);
#pragma unroll
    for (int m = 0; m < 4; ++m)
#pragma unroll
      for (int cf = 0; cf < 4; ++cf)
        acc[m][cf] = __builtin_amdgcn_mfma_f32_16x16x32_bf16(af[m], bv[cf], acc[m][cf], 0, 0, 0);
    // kmean partial: thread (sr, sg) sums unit sg of k-row sr (8 bf16)
    {
      uint2 u = *(const uint2*)(Al + sr*64 + ((sg ^ swz4(sr)) << 4));
      uint2 u2 = *(const uint2*)(Al + sr*64 + ((sg ^ swz4(sr)) << 4) + 8);
      const unsigned ua[4] = {u.x, u.y, u2.x, u2.y};
#pragma unroll
      for (int i = 0; i < 4; ++i){
        kms += bf2f((unsigned short)(ua[i] & 0xffffu));
        kms += bf2f((unsigned short)(ua[i] >> 16));
      }
    }
  }

  kms += __shfl_xor(kms, 1);
  kms += __shfl_xor(kms, 2);
  if ((tid & 3) == 0) kmp[((size_t)b*KSPLIT + ks)*D_ + sr] = kms;

  const int col = lane & 15, rg = lane >> 4;
#pragma unroll
  for (int m = 0; m < 4; ++m){
    const int d0 = wd + m*16 + rg*4;
#pragma unroll
    for (int cf = 0; cf < 4; ++cf){
      const int c = wc + cf*16 + col;
      ushort4 hv = {f2bf(acc[m][cf][0]), f2bf(acc[m][cf][1]),
                    f2bf(acc[m][cf][2]), f2bf(acc[m][cf][3])};
      *(ushort4*)(kvp + (((size_t)b*KSPLIT + ks)*C_ + c)*D_ + d0) = hv;
    }
  }
}

// ---------------------------------------------------------------------------
// KR: kvt[b][c][d] = (1/N) * sum_ks kvp[b][ks][c][d]; km[b][d] from kmp.
// (EXACT round-7 version — proven.)
// ---------------------------------------------------------------------------
__global__ __launch_bounds__(256) void kr_reduce(
    const unsigned short* __restrict__ kvp, const float* __restrict__ kmp,
    unsigned short* __restrict__ kvt, float* __restrict__ km)
{
  const int tid = threadIdx.x;
  const int bx = blockIdx.x, b = blockIdx.y;
  const float sc = 1.0f/(float)N_;
#pragma unroll
  for (int it = 0; it < 2; ++it){
    const int idx = (bx*2 + it)*256 + tid;      // 0..4095
    const int c = idx >> 4, dq = (idx & 15)*8;
    float s[8] = {};
    for (int ks = 0; ks < KSPLIT; ++ks){
      u16x8 v = *(const u16x8*)(kvp + (((size_t)b*KSPLIT + ks)*C_ + c)*D_ + dq);
#pragma unroll
      for (int i = 0; i < 8; ++i) s[i] += bf2f(v[i]);
    }
    u16x8 h;
#pragma unroll
    for (int i = 0; i < 8; ++i) h[i] = f2bf(s[i]*sc);
    *(u16x8*)(kvt + ((size_t)b*C_ + c)*D_ + dq) = h;
  }
  if (bx == 0 && tid < D_){
    float s = 0.f;
    for (int ks = 0; ks < KSPLIT; ++ks) s += kmp[((size_t)b*KSPLIT + ks)*D_ + tid];
    km[b*D_ + tid] = s*sc;
  }
}

// ---------------------------------------------------------------------------
// K3: attn[c][n] = (sum_d kvt[c][d]*qt[n][d]) / (q.km + 1e-6), bf16 out.
// (EXACT round-7 version — proven.)
// ---------------------------------------------------------------------------
__global__ __launch_bounds__(256) void k3_attn(
    const unsigned short* __restrict__ qt, const unsigned short* __restrict__ kvt,
    const float* __restrict__ km, unsigned short* __restrict__ attn)
{
  __shared__ __align__(16) char SM[256*64 + 64*64];  // 20KB
  char* Al = SM;                                 // [256 c][32 d] (16KB)
  char* Bl = SM + 256*64;                        // [64 n][32 d]  (4KB)
  unsigned short* P = (unsigned short*)SM;       // [128][72] bf16 (18KB overlay)
  __shared__ float kms[128];
  __shared__ float dens[64];
  const int tid = threadIdx.x, lane = tid & 63, wid = tid >> 6;
  const int n0 = blockIdx.x * 64;
  const int b  = blockIdx.y;
  if (tid < 128) kms[tid] = km[b*D_ + tid];
  const unsigned short* kvb = kvt + (size_t)b*C_*D_;
  const unsigned short* qtb = qt + ((size_t)b*N_ + n0)*D_;
  const int wc = wid*64;
  f32x4 acc[4][4] = {};
  float den = 0.f;

  for (int k0 = 0; k0 < D_; k0 += 32){
    __syncthreads();
    stage_glds<256>(kvb + k0, D_, Al);
    stage_glds<64>(qtb + k0, D_, Bl);
    __syncthreads();
    s16x8 af[4], bv4[4];
#pragma unroll
    for (int m = 0; m < 4; ++m)  af[m]  = ldsfrag(Al, wc + m*16 + (lane & 15), lane >> 4);
#pragma unroll
    for (int nf = 0; nf < 4; ++nf) bv4[nf] = ldsfrag(Bl, nf*16 + (lane & 15), lane >> 4);
#pragma unroll
    for (int m = 0; m < 4; ++m)
#pragma unroll
      for (int nf = 0; nf < 4; ++nf)
        acc[m][nf] = __builtin_amdgcn_mfma_f32_16x16x32_bf16(af[m], bv4[nf], acc[m][nf], 0, 0, 0);
    {
      const int nr = tid >> 2, g = tid & 3;
      uint4 u = *(const uint4*)(Bl + nr*64 + ((g ^ swz4(nr)) << 4));
      const float* kp = kms + k0 + g*8;
      const unsigned ua[4] = {u.x, u.y, u.z, u.w};
#pragma unroll
      for (int i = 0; i < 4; ++i){
        den += bf2f((unsigned short)(ua[i] & 0xffffu)) * kp[i*2];
        den += bf2f((unsigned short)(ua[i] >> 16))     * kp[i*2 + 1];
      }
    }
  }
  den += __shfl_xor(den, 1);
  den += __shfl_xor(den, 2);
  if ((tid & 3) == 0) dens[tid >> 2] = den;
  __syncthreads();   // GEMM LDS reads done + dens visible

  const int col = lane & 15, rg = lane >> 4;
  float rdv[4];
#pragma unroll
  for (int nf = 0; nf < 4; ++nf)
    rdv[nf] = 1.0f / (dens[nf*16 + col] + 1e-6f);

#pragma unroll
  for (int h = 0; h < 2; ++h){
    if ((wid >> 1) == h){
      const int lc = wc - h*128;   // 0 or 64
#pragma unroll
      for (int m = 0; m < 4; ++m)
#pragma unroll
        for (int nf = 0; nf < 4; ++nf)
#pragma unroll
          for (int j = 0; j < 4; ++j)
            P[(lc + m*16 + rg*4 + j)*72 + (nf*16 + col)] = f2bf(acc[m][nf][j] * rdv[nf]);
    }
    __syncthreads();
#pragma unroll
    for (int p = 0; p < 4; ++p){
      const int c = (tid >> 3) + p*32, ch = tid & 7;
      u16x8 v = *(const u16x8*)(P + c*72 + ch*8);
      *(u16x8*)(attn + ((size_t)b*C_ + h*128 + c)*N_ + n0 + ch*8) = v;
    }
    __syncthreads();
  }
}

// ---------------------------------------------------------------------------
// K4: out = attn + depthwise3x3(x) + pe_b. Plane per block, 4-wide along w,
// zero-padded top/bottom LDS rows. M=0: x fp32 (r7 proven). M=1: x from xb16.
// (EXACT round-10 version — proven.)
// ---------------------------------------------------------------------------
template<int M>
__global__ __launch_bounds__(256) void k4_pe(
    const float* __restrict__ x, const unsigned short* __restrict__ xb16,
    const unsigned short* __restrict__ attn,
    const float* __restrict__ pw, const float* __restrict__ pb,
    float* __restrict__ out)
{
  __shared__ float xs_raw[58*56 + 8];
  float* xs = xs_raw + 4;          // slack so xs[-1] stays in-bounds
  const int tid = threadIdx.x;
  const int ch = blockIdx.x, b = blockIdx.y;
  if (tid < 14)      ((float4*)xs)[tid] = (float4){0.f,0.f,0.f,0.f};        // pad row 0
  else if (tid < 28) ((float4*)xs)[784 + tid] = (float4){0.f,0.f,0.f,0.f};  // pad row 57
  if (M){
    const unsigned short* xp = xb16 + ((size_t)b*C_ + ch)*N_;
    for (int i = tid; i < 392; i += 256){
      u16x8 v = ((const u16x8*)xp)[i];
      float4 f0 = {bf2f(v[0]), bf2f(v[1]), bf2f(v[2]), bf2f(v[3])};
      float4 f1 = {bf2f(v[4]), bf2f(v[5]), bf2f(v[6]), bf2f(v[7])};
      ((float4*)xs)[14 + 2*i]     = f0;
      ((float4*)xs)[14 + 2*i + 1] = f1;
    }
  } else {
    const float* xp = x + ((size_t)b*C_ + ch)*N_;
    for (int i = tid; i < 784; i += 256)
      ((float4*)xs)[14 + i] = ((const float4*)xp)[i];
  }
  const float* wp = pw + ch*9;
  float wgt[9];
#pragma unroll
  for (int i = 0; i < 9; ++i) wgt[i] = wp[i];
  const float bias = pb[ch];
  __syncthreads();
  const unsigned short* ap = attn + ((size_t)b*C_ + ch)*N_;
  float* op = out + ((size_t)b*C_ + ch)*N_;
  for (int u = tid; u < 784; u += 256) {
    const int row = u / 14, g = u - row*14;     // output row, float4 group
    float o0 = bias, o1 = bias, o2 = bias, o3 = bias;
#pragma unroll
    for (int rr = 0; rr < 3; ++rr){
      const float* rp = xs + (row + rr)*56 + g*4;   // padded rows row..row+2
      float4 cv = *(const float4*)rp;
      float lf = (g > 0)  ? rp[-1] : 0.f;
      float rt = (g < 13) ? rp[4]  : 0.f;
      const float wl = wgt[rr*3], wc_ = wgt[rr*3+1], wr = wgt[rr*3+2];
      o0 += wl*lf   + wc_*cv.x + wr*cv.y;
      o1 += wl*cv.x + wc_*cv.y + wr*cv.z;
      o2 += wl*cv.y + wc_*cv.z + wr*cv.w;
      o3 += wl*cv.z + wc_*cv.w + wr*rt;
    }
    ushort4 av = *(const ushort4*)(ap + u*4);
    float4 ov = {o0 + bf2f(av.x), o1 + bf2f(av.y), o2 + bf2f(av.z), o3 + bf2f(av.w)};
    *(float4*)(op + u*4) = ov;
  }
}

extern "C" void kernel_launch(void* const* d_in, const int* in_sizes, int n_in,
                              void* d_out, int out_size, void* d_ws, size_t ws_size,
                              hipStream_t stream) {
  (void)in_sizes; (void)n_in; (void)out_size;
  const float* x   = (const float*)d_in[0];
  const float* qkw = (const float*)d_in[1];
  const float* qkb = (const float*)d_in[2];
  const float* pew = (const float*)d_in[3];
  const float* peb = (const float*)d_in[4];
  float* out = (float*)d_out;

  // Base ws layout (104.9 MB, round-7 proven). Optional xb16 slot appended
  // (51.4 MB) used only when ws_size is large enough (path A).
  unsigned short* xts  = (unsigned short*)d_ws;                 // [B][N][C] bf16
  unsigned short* kbuf = xts + (size_t)B_*N_*C_;                // [B][128][N] bf16
  unsigned short* qt   = kbuf + (size_t)B_*D_*N_;               // [B][N][128] bf16
  unsigned short* kvt  = qt   + (size_t)B_*N_*D_;               // [B][256][128] bf16
  float* km  = (float*)(kvt + (size_t)B_*C_*D_);                // [B][128] f32
  unsigned short* xb16 = (unsigned short*)(km + (size_t)B_*D_); // [B][C][N] bf16 (path A)
  unsigned short* wb   = kvt;                                   // [256][256] bf16 (alias)
  unsigned short* kvp  = xts;                                   // [B][7][256][128] bf16 (alias)
  float* kmp = (float*)(kvp + (size_t)B_*KSPLIT*C_*D_);         // [B][7][128] f32 (in xt slot)
  unsigned short* attn = xts;                                   // [B][256][N] bf16 (alias)

  const size_t need_a = ((size_t)B_*N_*C_ + (size_t)B_*D_*N_ + (size_t)B_*N_*D_
                       + (size_t)B_*C_*D_)*2 + (size_t)B_*D_*4
                       + (size_t)B_*C_*N_*2;    // = 156,254,208 bytes
  const bool big = ws_size >= need_a;

  k0_w<<<dim3(64), 256, 0, stream>>>(qkw, wb);
  if (big){
    k0_t<1><<<dim3(N_/64, C_/128, B_), 256, 0, stream>>>(x, xts, xb16);
  } else {
    k0_t<0><<<dim3(N_/64, C_/128, B_), 256, 0, stream>>>(x, xts, xb16);
  }
  k1_qk<<<dim3(N_/64, B_), 256, 0, stream>>>(xts, wb, qkb, kbuf, qt);
  if (big){
    k2_kv<1><<<dim3(KSPLIT, B_), 512, 0, stream>>>(kbuf, x, xb16, kvp, kmp);
  } else {
    k2_kv<0><<<dim3(KSPLIT, B_), 512, 0, stream>>>(kbuf, x, xb16, kvp, kmp);
  }
  kr_reduce<<<dim3(8, B_), 256, 0, stream>>>(kvp, kmp, kvt, km);
  k3_attn<<<dim3(N_/64, B_), 256, 0, stream>>>(qt, kvt, km, attn);
  if (big){
    k4_pe<1><<<dim3(C_, B_), 256, 0, stream>>>(x, xb16, attn, pew, peb, out);
  } else {
    k4_pe<0><<<dim3(C_, B_), 256, 0, stream>>>(x, xb16, attn, pew, peb, out);
  }
}

// Round 13
// 177.554 us; speedup vs baseline: 1.0648x; 1.0648x over previous
//
#include <hip/hip_runtime.h>

#define B_ 32
#define C_ 256
#define D_ 128
#define HH 56
#define WW 56
#define N_ 3136
#define KSPLIT 7
#define KRANGE 448   // n per K-split in k2: 14 steps of 32

typedef float f32x4 __attribute__((ext_vector_type(4)));
typedef short s16x8 __attribute__((ext_vector_type(8)));
typedef unsigned short u16x8 __attribute__((ext_vector_type(8)));

// Row swizzle for [R][32-bf16] LDS tiles (64B rows = 4x16B units).
__device__ __forceinline__ int swz4(int r){
  return (r & 3) ^ (((r >> 2) & 1) << 1) ^ ((r >> 3) & 1);
}
__device__ __forceinline__ unsigned short f2bf(float f){
  unsigned u = __float_as_uint(f);
  u += 0x7fffu + ((u >> 16) & 1u);           // RNE
  return (unsigned short)(u >> 16);
}
__device__ __forceinline__ float bf2f(unsigned short h){
  return __uint_as_float(((unsigned)h) << 16);
}
__device__ __forceinline__ float elu1(float v){
  return v > 0.f ? v + 1.f : __expf(v);      // elu(v)+1
}
// HW packed f32x2 -> bf16x2 (RNE), 1 instr for 2 values.
__device__ __forceinline__ unsigned cvtpk(float lo, float hi){
  unsigned r;
  asm("v_cvt_pk_bf16_f32 %0, %1, %2" : "=v"(r) : "v"(lo), "v"(hi));
  return r;
}

// Stage [R rows][32 bf16] from bf16 global (pitch ld) into swizzled LDS via
// global_load_lds: dest is lane-linear, swizzle pre-applied on global source.
// 256-thread variant.
template<int R>
__device__ __forceinline__ void stage_glds(const unsigned short* gp, int ld, char* lds){
  const int tid = threadIdx.x;
  const int wid = tid >> 6;
#pragma unroll
  for (int q = 0; q < R/64; ++q){
    const int slot = q*256 + tid;            // = r*4 + unit
    const int r = slot >> 2, gi = slot & 3;
    const int u = gi ^ swz4(r);
    const unsigned short* ga = gp + r*ld + u*8;
    char* lb = lds + (q*256 + wid*64)*16;    // wave-uniform LDS base
    __builtin_amdgcn_global_load_lds(
        (__attribute__((address_space(1))) void*)ga,
        (__attribute__((address_space(3))) void*)lb, 16, 0, 0);
  }
}

__device__ __forceinline__ s16x8 ldsfrag(const char* lds, int r, int g){
  return *(const s16x8*)(lds + r*64 + ((g ^ swz4(r)) << 4));
}

// ---------------------------------------------------------------------------
// K0w: W fp32 -> bf16.
// ---------------------------------------------------------------------------
__global__ __launch_bounds__(256) void k0_w(
    const float* __restrict__ w, unsigned short* __restrict__ wb)
{
  const int i = blockIdx.x*256 + threadIdx.x;   // 16384 float4s
  float4 v = *(const float4*)(w + (size_t)i*4);
  uint2 h = {cvtpk(v.x, v.y), cvtpk(v.z, v.w)};
  *(uint2*)(wb + (size_t)i*4) = h;
}

// ---------------------------------------------------------------------------
// K0c: xb16[b][c][n] = bf16(x) — pure BW copy (big path only). 8 elems/thread.
// ---------------------------------------------------------------------------
__global__ __launch_bounds__(256) void k0_c(
    const float* __restrict__ x, unsigned short* __restrict__ xb16)
{
  const size_t i = (size_t)blockIdx.x*256 + threadIdx.x;   // 8-elem group
  float4 v0 = *(const float4*)(x + i*8);
  float4 v1 = *(const float4*)(x + i*8 + 4);
  uint4 h = {cvtpk(v0.x, v0.y), cvtpk(v0.z, v0.w),
             cvtpk(v1.x, v1.y), cvtpk(v1.z, v1.w)};
  *(uint4*)(xb16 + i*8) = h;
}

// ---------------------------------------------------------------------------
// K0t2: xt[b][n][c] = transpose(xb16[b][c][n]) — big path. Exact r10 T-based
// transpose structure (proven full-line xt writes), but input is bf16 and
// L3-warm (just written by k0_c): half the read bytes, lower latency.
// cvtpk(bf2f(h)) is identity on bf16 values -> bit-identical xt vs r10.
// ---------------------------------------------------------------------------
__global__ __launch_bounds__(256) void k0_t2(
    const unsigned short* __restrict__ xb16, unsigned short* __restrict__ xt)
{
  __shared__ float T[64][65];
  const int tid = threadIdx.x;
  const int n0 = blockIdx.x*64, c0 = blockIdx.y*64, b = blockIdx.z;
  const int r = tid >> 2, ch = tid & 3;
  u16x8 u = *(const u16x8*)(xb16 + ((size_t)(b*C_ + c0 + r))*N_ + n0 + ch*8);
#pragma unroll
  for (int j = 0; j < 8; ++j) T[r][ch*8 + j] = bf2f(u[j]);
  __syncthreads();
  const int nn = tid >> 2, cq = tid & 3;
  unsigned h[8];
#pragma unroll
  for (int j = 0; j < 8; ++j)
    h[j] = cvtpk(T[cq*16 + 2*j][nn], T[cq*16 + 2*j + 1][nn]);
  unsigned short* dst = xt + ((size_t)b*N_ + n0 + nn)*C_ + c0 + cq*16;
  *(uint4*)dst       = (uint4){h[0], h[1], h[2], h[3]};
  *(uint4*)(dst + 8) = (uint4){h[4], h[5], h[6], h[7]};
}

// ---------------------------------------------------------------------------
// K0t: fused transpose + optional xb16 (EXACT round-10 version — proven).
// Used only on the small-ws fallback path (M=0).
// ---------------------------------------------------------------------------
template<int M>
__global__ __launch_bounds__(256) void k0_t(
    const float* __restrict__ x, unsigned short* __restrict__ xt,
    unsigned short* __restrict__ xb16)
{
  __shared__ float T[64][65];
  const int tid = threadIdx.x;
  const int n0 = blockIdx.x*64, c0 = blockIdx.y*64, b = blockIdx.z;
  const float* xb = x + ((size_t)b*C_ + c0)*N_ + n0;
#pragma unroll
  for (int q = 0; q < 4; ++q){
    const int cr = q*16 + (tid >> 4), nc = (tid & 15)*4;
    float4 v = *(const float4*)(xb + (size_t)cr*N_ + nc);
    T[cr][nc+0] = v.x; T[cr][nc+1] = v.y; T[cr][nc+2] = v.z; T[cr][nc+3] = v.w;
    if (M){
      uint2 hh = {cvtpk(v.x, v.y), cvtpk(v.z, v.w)};
      *(uint2*)(xb16 + ((size_t)b*C_ + c0 + cr)*N_ + n0 + nc) = hh;
    }
  }
  __syncthreads();
  const int nn = tid >> 2, cq = tid & 3;
  unsigned h[8];
#pragma unroll
  for (int j = 0; j < 8; ++j)
    h[j] = cvtpk(T[cq*16 + 2*j][nn], T[cq*16 + 2*j + 1][nn]);
  unsigned short* dst = xt + ((size_t)b*N_ + n0 + nn)*C_ + c0 + cq*16;
  *(uint4*)dst       = (uint4){h[0], h[1], h[2], h[3]};
  *(uint4*)(dst + 8) = (uint4){h[4], h[5], h[6], h[7]};
}

// ---------------------------------------------------------------------------
// K1: qk = elu(W.x + b)+1.  MFMA GEMM M=256(o) x BN=64(n) x K=256(c).
// Pure global_load_lds staging. Waves 0-1 -> q half stored qt[b][n][d];
// waves 2-3 -> k half kbuf[b][d][n].  (EXACT round-7 version — proven.)
// ---------------------------------------------------------------------------
__global__ __launch_bounds__(256) void k1_qk(
    const unsigned short* __restrict__ xt, const unsigned short* __restrict__ wb,
    const float* __restrict__ bias,
    unsigned short* __restrict__ kbuf, unsigned short* __restrict__ qt)
{
  __shared__ __align__(16) char Al[256*64];  // [256 o][32 c] bf16, swizzled
  __shared__ __align__(16) char Bl[64*64];   // [64 n][32 c]  bf16, swizzled
  const int tid = threadIdx.x, lane = tid & 63, wid = tid >> 6;
  const int n0 = blockIdx.x * 64;
  const int b  = blockIdx.y;
  const unsigned short* xtb = xt + ((size_t)b*N_ + n0)*C_;
  const int wo = wid*64;
  f32x4 acc[4][4] = {};

  for (int k0 = 0; k0 < C_; k0 += 32){
    __syncthreads();
    stage_glds<256>(wb + k0, C_, Al);
    stage_glds<64>(xtb + k0, C_, Bl);
    __syncthreads();
    s16x8 af[4], bv4[4];
#pragma unroll
    for (int m = 0; m < 4; ++m)  af[m]  = ldsfrag(Al, wo + m*16 + (lane & 15), lane >> 4);
#pragma unroll
    for (int nf = 0; nf < 4; ++nf) bv4[nf] = ldsfrag(Bl, nf*16 + (lane & 15), lane >> 4);
#pragma unroll
    for (int m = 0; m < 4; ++m)
#pragma unroll
      for (int nf = 0; nf < 4; ++nf)
        acc[m][nf] = __builtin_amdgcn_mfma_f32_16x16x32_bf16(af[m], bv4[nf], acc[m][nf], 0, 0, 0);
  }

  const int col = lane & 15, rg = lane >> 4;
  if (wid < 2){
    // q half -> qt[b][n][d]
#pragma unroll
    for (int m = 0; m < 4; ++m){
      const int db = wo + m*16 + rg*4;
      const float b0 = bias[db], b1 = bias[db+1], b2 = bias[db+2], b3 = bias[db+3];
#pragma unroll
      for (int nf = 0; nf < 4; ++nf){
        const int n = n0 + nf*16 + col;
        f32x4 a = acc[m][nf];
        uint2 hv = {cvtpk(elu1(a[0]+b0), elu1(a[1]+b1)),
                    cvtpk(elu1(a[2]+b2), elu1(a[3]+b3))};
        *(uint2*)(qt + ((size_t)b*N_ + n)*D_ + db) = hv;
      }
    }
  } else {
    // k half -> kbuf[b][d][n]
#pragma unroll
    for (int m = 0; m < 4; ++m)
#pragma unroll
      for (int j = 0; j < 4; ++j){
        const int d = wo - 128 + m*16 + rg*4 + j;
        const float bb = bias[128 + d];
#pragma unroll
        for (int nf = 0; nf < 4; ++nf){
          const int n = n0 + nf*16 + col;
          kbuf[((size_t)b*D_ + d)*N_ + n] = f2bf(elu1(acc[m][nf][j] + bb));
        }
      }
  }
}

// ---------------------------------------------------------------------------
// K2: kv partials = sum_n k[d][n]*x[c][n] over K-split. M=128(d) x BN=256(c)
// x K=448(n). 512 threads / 8 waves. Partials stored [c][d]. Fuses kmean.
// M=0: B from x fp32 + cvt_pk (r7 proven). M=1: B pure DMA from xb16.
// (EXACT round-10 version — proven.)
// ---------------------------------------------------------------------------
template<int M>
__global__ __launch_bounds__(512) void k2_kv(
    const unsigned short* __restrict__ kbuf, const float* __restrict__ x,
    const unsigned short* __restrict__ xb16,
    unsigned short* __restrict__ kvp, float* __restrict__ kmp)
{
  __shared__ __align__(16) char Al[128*64];  // [128 d][32 n]
  __shared__ __align__(16) char Bl[256*64];  // [256 c][32 n]
  const int tid = threadIdx.x, lane = tid & 63, wid = tid >> 6;  // 8 waves
  const int ks = blockIdx.x;
  const int b  = blockIdx.y;
  const unsigned short* kb = kbuf + (size_t)b*D_*N_ + ks*KRANGE;
  const float* xb = x + (size_t)b*C_*N_ + ks*KRANGE;
  const unsigned short* xbb = xb16 + (size_t)b*C_*N_ + ks*KRANGE;
  const int wd = (wid >> 2)*64, wc = (wid & 3)*64;
  f32x4 acc[4][4] = {};
  float kms = 0.f;
  const int sr = tid >> 2, sg = tid & 3;     // staging/kms row & unit

  for (int t = 0; t < KRANGE/32; ++t){
    __syncthreads();
    // A: 128 rows x 4 units = 512 slots, one global_load_lds per thread
    {
      const int u = sg ^ swz4(sr);
      const unsigned short* ga = kb + (size_t)sr*N_ + t*32 + u*8;
      char* lb = Al + (wid*64)*16;           // wave-uniform base; unit = tid
      __builtin_amdgcn_global_load_lds(
          (__attribute__((address_space(1))) void*)ga,
          (__attribute__((address_space(3))) void*)lb, 16, 0, 0);
    }
    if (M){
      // B: 256 rows x 4 units = 1024 slots, two DMAs per thread
#pragma unroll
      for (int q = 0; q < 2; ++q){
        const int slot = q*512 + tid;
        const int r = slot >> 2, gi = slot & 3;
        const int u = gi ^ swz4(r);
        const unsigned short* ga = xbb + (size_t)r*N_ + t*32 + u*8;
        char* lb = Bl + (q*512 + wid*64)*16;
        __builtin_amdgcn_global_load_lds(
            (__attribute__((address_space(1))) void*)ga,
            (__attribute__((address_space(3))) void*)lb, 16, 0, 0);
      }
    } else {
      // B: x[c][n] fp32 -> bf16 (cvt_pk); 256 rows x 32 n, 16 elems/thread
#pragma unroll
      for (int q = 0; q < 4; ++q){
        int idx = q*512 + tid;                 // 0..2047
        int cc = idx >> 3, n4 = (idx & 7)*4;
        float4 v = *(const float4*)(xb + (size_t)cc*N_ + t*32 + n4);
        uint2 h = {cvtpk(v.x, v.y), cvtpk(v.z, v.w)};
        *(uint2*)(Bl + cc*64 + ((n4*2) ^ (swz4(cc) << 4))) = h;
      }
    }
    __syncthreads();
    s16x8 af[4], bv[4];
#pragma unroll
    for (int m = 0; m < 4; ++m)  af[m] = ldsfrag(Al, wd + m*16 + (lane & 15), lane >> 4);
#pragma unroll
    for (int cf = 0; cf < 4; ++cf) bv[cf] = ldsfrag(Bl, wc + cf*16 + (lane & 15), lane >> 4);
#pragma unroll
    for (int m = 0; m < 4; ++m)
#pragma unroll
      for (int cf = 0; cf < 4; ++cf)
        acc[m][cf] = __builtin_amdgcn_mfma_f32_16x16x32_bf16(af[m], bv[cf], acc[m][cf], 0, 0, 0);
    // kmean partial: thread (sr, sg) sums unit sg of k-row sr (8 bf16)
    {
      uint2 u = *(const uint2*)(Al + sr*64 + ((sg ^ swz4(sr)) << 4));
      uint2 u2 = *(const uint2*)(Al + sr*64 + ((sg ^ swz4(sr)) << 4) + 8);
      const unsigned ua[4] = {u.x, u.y, u2.x, u2.y};
#pragma unroll
      for (int i = 0; i < 4; ++i){
        kms += bf2f((unsigned short)(ua[i] & 0xffffu));
        kms += bf2f((unsigned short)(ua[i] >> 16));
      }
    }
  }

  kms += __shfl_xor(kms, 1);
  kms += __shfl_xor(kms, 2);
  if ((tid & 3) == 0) kmp[((size_t)b*KSPLIT + ks)*D_ + sr] = kms;

  const int col = lane & 15, rg = lane >> 4;
#pragma unroll
  for (int m = 0; m < 4; ++m){
    const int d0 = wd + m*16 + rg*4;
#pragma unroll
    for (int cf = 0; cf < 4; ++cf){
      const int c = wc + cf*16 + col;
      ushort4 hv = {f2bf(acc[m][cf][0]), f2bf(acc[m][cf][1]),
                    f2bf(acc[m][cf][2]), f2bf(acc[m][cf][3])};
      *(ushort4*)(kvp + (((size_t)b*KSPLIT + ks)*C_ + c)*D_ + d0) = hv;
    }
  }
}

// ---------------------------------------------------------------------------
// KR: kvt[b][c][d] = (1/N) * sum_ks kvp[b][ks][c][d]; km[b][d] from kmp.
// (EXACT round-7 version — proven.)
// ---------------------------------------------------------------------------
__global__ __launch_bounds__(256) void kr_reduce(
    const unsigned short* __restrict__ kvp, const float* __restrict__ kmp,
    unsigned short* __restrict__ kvt, float* __restrict__ km)
{
  const int tid = threadIdx.x;
  const int bx = blockIdx.x, b = blockIdx.y;
  const float sc = 1.0f/(float)N_;
#pragma unroll
  for (int it = 0; it < 2; ++it){
    const int idx = (bx*2 + it)*256 + tid;      // 0..4095
    const int c = idx >> 4, dq = (idx & 15)*8;
    float s[8] = {};
    for (int ks = 0; ks < KSPLIT; ++ks){
      u16x8 v = *(const u16x8*)(kvp + (((size_t)b*KSPLIT + ks)*C_ + c)*D_ + dq);
#pragma unroll
      for (int i = 0; i < 8; ++i) s[i] += bf2f(v[i]);
    }
    u16x8 h;
#pragma unroll
    for (int i = 0; i < 8; ++i) h[i] = f2bf(s[i]*sc);
    *(u16x8*)(kvt + ((size_t)b*C_ + c)*D_ + dq) = h;
  }
  if (bx == 0 && tid < D_){
    float s = 0.f;
    for (int ks = 0; ks < KSPLIT; ++ks) s += kmp[((size_t)b*KSPLIT + ks)*D_ + tid];
    km[b*D_ + tid] = s*sc;
  }
}

// ---------------------------------------------------------------------------
// K3: attn[c][n] = (sum_d kvt[c][d]*qt[n][d]) / (q.km + 1e-6), bf16 out.
// (EXACT round-7 version — proven.)
// ---------------------------------------------------------------------------
__global__ __launch_bounds__(256) void k3_attn(
    const unsigned short* __restrict__ qt, const unsigned short* __restrict__ kvt,
    const float* __restrict__ km, unsigned short* __restrict__ attn)
{
  __shared__ __align__(16) char SM[256*64 + 64*64];  // 20KB
  char* Al = SM;                                 // [256 c][32 d] (16KB)
  char* Bl = SM + 256*64;                        // [64 n][32 d]  (4KB)
  unsigned short* P = (unsigned short*)SM;       // [128][72] bf16 (18KB overlay)
  __shared__ float kms[128];
  __shared__ float dens[64];
  const int tid = threadIdx.x, lane = tid & 63, wid = tid >> 6;
  const int n0 = blockIdx.x * 64;
  const int b  = blockIdx.y;
  if (tid < 128) kms[tid] = km[b*D_ + tid];
  const unsigned short* kvb = kvt + (size_t)b*C_*D_;
  const unsigned short* qtb = qt + ((size_t)b*N_ + n0)*D_;
  const int wc = wid*64;
  f32x4 acc[4][4] = {};
  float den = 0.f;

  for (int k0 = 0; k0 < D_; k0 += 32){
    __syncthreads();
    stage_glds<256>(kvb + k0, D_, Al);
    stage_glds<64>(qtb + k0, D_, Bl);
    __syncthreads();
    s16x8 af[4], bv4[4];
#pragma unroll
    for (int m = 0; m < 4; ++m)  af[m]  = ldsfrag(Al, wc + m*16 + (lane & 15), lane >> 4);
#pragma unroll
    for (int nf = 0; nf < 4; ++nf) bv4[nf] = ldsfrag(Bl, nf*16 + (lane & 15), lane >> 4);
#pragma unroll
    for (int m = 0; m < 4; ++m)
#pragma unroll
      for (int nf = 0; nf < 4; ++nf)
        acc[m][nf] = __builtin_amdgcn_mfma_f32_16x16x32_bf16(af[m], bv4[nf], acc[m][nf], 0, 0, 0);
    {
      const int nr = tid >> 2, g = tid & 3;
      uint4 u = *(const uint4*)(Bl + nr*64 + ((g ^ swz4(nr)) << 4));
      const float* kp = kms + k0 + g*8;
      const unsigned ua[4] = {u.x, u.y, u.z, u.w};
#pragma unroll
      for (int i = 0; i < 4; ++i){
        den += bf2f((unsigned short)(ua[i] & 0xffffu)) * kp[i*2];
        den += bf2f((unsigned short)(ua[i] >> 16))     * kp[i*2 + 1];
      }
    }
  }
  den += __shfl_xor(den, 1);
  den += __shfl_xor(den, 2);
  if ((tid & 3) == 0) dens[tid >> 2] = den;
  __syncthreads();   // GEMM LDS reads done + dens visible

  const int col = lane & 15, rg = lane >> 4;
  float rdv[4];
#pragma unroll
  for (int nf = 0; nf < 4; ++nf)
    rdv[nf] = 1.0f / (dens[nf*16 + col] + 1e-6f);

#pragma unroll
  for (int h = 0; h < 2; ++h){
    if ((wid >> 1) == h){
      const int lc = wc - h*128;   // 0 or 64
#pragma unroll
      for (int m = 0; m < 4; ++m)
#pragma unroll
        for (int nf = 0; nf < 4; ++nf)
#pragma unroll
          for (int j = 0; j < 4; ++j)
            P[(lc + m*16 + rg*4 + j)*72 + (nf*16 + col)] = f2bf(acc[m][nf][j] * rdv[nf]);
    }
    __syncthreads();
#pragma unroll
    for (int p = 0; p < 4; ++p){
      const int c = (tid >> 3) + p*32, ch = tid & 7;
      u16x8 v = *(const u16x8*)(P + c*72 + ch*8);
      *(u16x8*)(attn + ((size_t)b*C_ + h*128 + c)*N_ + n0 + ch*8) = v;
    }
    __syncthreads();
  }
}

// ---------------------------------------------------------------------------
// K4: out = attn + depthwise3x3(x) + pe_b. Plane per block, 4-wide along w,
// zero-padded top/bottom LDS rows. M=0: x fp32 (r7 proven). M=1: x from xb16.
// (EXACT round-10 version — proven.)
// ---------------------------------------------------------------------------
template<int M>
__global__ __launch_bounds__(256) void k4_pe(
    const float* __restrict__ x, const unsigned short* __restrict__ xb16,
    const unsigned short* __restrict__ attn,
    const float* __restrict__ pw, const float* __restrict__ pb,
    float* __restrict__ out)
{
  __shared__ float xs_raw[58*56 + 8];
  float* xs = xs_raw + 4;          // slack so xs[-1] stays in-bounds
  const int tid = threadIdx.x;
  const int ch = blockIdx.x, b = blockIdx.y;
  if (tid < 14)      ((float4*)xs)[tid] = (float4){0.f,0.f,0.f,0.f};        // pad row 0
  else if (tid < 28) ((float4*)xs)[784 + tid] = (float4){0.f,0.f,0.f,0.f};  // pad row 57
  if (M){
    const unsigned short* xp = xb16 + ((size_t)b*C_ + ch)*N_;
    for (int i = tid; i < 392; i += 256){
      u16x8 v = ((const u16x8*)xp)[i];
      float4 f0 = {bf2f(v[0]), bf2f(v[1]), bf2f(v[2]), bf2f(v[3])};
      float4 f1 = {bf2f(v[4]), bf2f(v[5]), bf2f(v[6]), bf2f(v[7])};
      ((float4*)xs)[14 + 2*i]     = f0;
      ((float4*)xs)[14 + 2*i + 1] = f1;
    }
  } else {
    const float* xp = x + ((size_t)b*C_ + ch)*N_;
    for (int i = tid; i < 784; i += 256)
      ((float4*)xs)[14 + i] = ((const float4*)xp)[i];
  }
  const float* wp = pw + ch*9;
  float wgt[9];
#pragma unroll
  for (int i = 0; i < 9; ++i) wgt[i] = wp[i];
  const float bias = pb[ch];
  __syncthreads();
  const unsigned short* ap = attn + ((size_t)b*C_ + ch)*N_;
  float* op = out + ((size_t)b*C_ + ch)*N_;
  for (int u = tid; u < 784; u += 256) {
    const int row = u / 14, g = u - row*14;     // output row, float4 group
    float o0 = bias, o1 = bias, o2 = bias, o3 = bias;
#pragma unroll
    for (int rr = 0; rr < 3; ++rr){
      const float* rp = xs + (row + rr)*56 + g*4;   // padded rows row..row+2
      float4 cv = *(const float4*)rp;
      float lf = (g > 0)  ? rp[-1] : 0.f;
      float rt = (g < 13) ? rp[4]  : 0.f;
      const float wl = wgt[rr*3], wc_ = wgt[rr*3+1], wr = wgt[rr*3+2];
      o0 += wl*lf   + wc_*cv.x + wr*cv.y;
      o1 += wl*cv.x + wc_*cv.y + wr*cv.z;
      o2 += wl*cv.y + wc_*cv.z + wr*cv.w;
      o3 += wl*cv.z + wc_*cv.w + wr*rt;
    }
    ushort4 av = *(const ushort4*)(ap + u*4);
    float4 ov = {o0 + bf2f(av.x), o1 + bf2f(av.y), o2 + bf2f(av.z), o3 + bf2f(av.w)};
    *(float4*)(op + u*4) = ov;
  }
}

extern "C" void kernel_launch(void* const* d_in, const int* in_sizes, int n_in,
                              void* d_out, int out_size, void* d_ws, size_t ws_size,
                              hipStream_t stream) {
  (void)in_sizes; (void)n_in; (void)out_size;
  const float* x   = (const float*)d_in[0];
  const float* qkw = (const float*)d_in[1];
  const float* qkb = (const float*)d_in[2];
  const float* pew = (const float*)d_in[3];
  const float* peb = (const float*)d_in[4];
  float* out = (float*)d_out;

  // Base ws layout (104.9 MB, round-7 proven). Optional xb16 slot appended
  // (51.4 MB) used only when ws_size is large enough (path A).
  unsigned short* xts  = (unsigned short*)d_ws;                 // [B][N][C] bf16
  unsigned short* kbuf = xts + (size_t)B_*N_*C_;                // [B][128][N] bf16
  unsigned short* qt   = kbuf + (size_t)B_*D_*N_;               // [B][N][128] bf16
  unsigned short* kvt  = qt   + (size_t)B_*N_*D_;               // [B][256][128] bf16
  float* km  = (float*)(kvt + (size_t)B_*C_*D_);                // [B][128] f32
  unsigned short* xb16 = (unsigned short*)(km + (size_t)B_*D_); // [B][C][N] bf16 (path A)
  unsigned short* wb   = kvt;                                   // [256][256] bf16 (alias)
  unsigned short* kvp  = xts;                                   // [B][7][256][128] bf16 (alias)
  float* kmp = (float*)(kvp + (size_t)B_*KSPLIT*C_*D_);         // [B][7][128] f32 (in xt slot)
  unsigned short* attn = xts;                                   // [B][256][N] bf16 (alias)

  const size_t need_a = ((size_t)B_*N_*C_ + (size_t)B_*D_*N_ + (size_t)B_*N_*D_
                       + (size_t)B_*C_*D_)*2 + (size_t)B_*D_*4
                       + (size_t)B_*C_*N_*2;    // = 156,254,208 bytes
  const bool big = ws_size >= need_a;

  k0_w<<<dim3(64), 256, 0, stream>>>(qkw, wb);
  if (big){
    // split: pure-BW copy, then transpose from L3-warm bf16
    k0_c <<<dim3((int)((size_t)B_*C_*N_/2048)), 256, 0, stream>>>(x, xb16);
    k0_t2<<<dim3(N_/64, C_/64, B_),             256, 0, stream>>>(xb16, xts);
  } else {
    k0_t<0><<<dim3(N_/64, C_/64, B_), 256, 0, stream>>>(x, xts, xb16);
  }
  k1_qk<<<dim3(N_/64, B_), 256, 0, stream>>>(xts, wb, qkb, kbuf, qt);
  if (big){
    k2_kv<1><<<dim3(KSPLIT, B_), 512, 0, stream>>>(kbuf, x, xb16, kvp, kmp);
  } else {
    k2_kv<0><<<dim3(KSPLIT, B_), 512, 0, stream>>>(kbuf, x, xb16, kvp, kmp);
  }
  kr_reduce<<<dim3(8, B_), 256, 0, stream>>>(kvp, kmp, kvt, km);
  k3_attn<<<dim3(N_/64, B_), 256, 0, stream>>>(qt, kvt, km, attn);
  if (big){
    k4_pe<1><<<dim3(C_, B_), 256, 0, stream>>>(x, xb16, attn, pew, peb, out);
  } else {
    k4_pe<0><<<dim3(C_, B_), 256, 0, stream>>>(x, xb16, attn, pew, peb, out);
  }
}

// Round 14
// 165.684 us; speedup vs baseline: 1.1411x; 1.0716x over previous
//
#include <hip/hip_runtime.h>

#define B_ 32
#define C_ 256
#define D_ 128
#define HH 56
#define WW 56
#define N_ 3136
#define KSPLIT 7
#define KRANGE 448   // n per K-split in k2: 14 steps of 32

typedef float f32x4 __attribute__((ext_vector_type(4)));
typedef short s16x8 __attribute__((ext_vector_type(8)));
typedef unsigned short u16x8 __attribute__((ext_vector_type(8)));

// Row swizzle for [R][32-bf16] LDS tiles (64B rows = 4x16B units).
__device__ __forceinline__ int swz4(int r){
  return (r & 3) ^ (((r >> 2) & 1) << 1) ^ ((r >> 3) & 1);
}
__device__ __forceinline__ unsigned short f2bf(float f){
  unsigned u = __float_as_uint(f);
  u += 0x7fffu + ((u >> 16) & 1u);           // RNE
  return (unsigned short)(u >> 16);
}
__device__ __forceinline__ float bf2f(unsigned short h){
  return __uint_as_float(((unsigned)h) << 16);
}
__device__ __forceinline__ float elu1(float v){
  return v > 0.f ? v + 1.f : __expf(v);      // elu(v)+1
}
// HW packed f32x2 -> bf16x2 (RNE), 1 instr for 2 values.
__device__ __forceinline__ unsigned cvtpk(float lo, float hi){
  unsigned r;
  asm("v_cvt_pk_bf16_f32 %0, %1, %2" : "=v"(r) : "v"(lo), "v"(hi));
  return r;
}

// Stage [R rows][32 bf16] from bf16 global (pitch ld) into swizzled LDS via
// global_load_lds: dest is lane-linear, swizzle pre-applied on global source.
// 256-thread variant.
template<int R>
__device__ __forceinline__ void stage_glds(const unsigned short* gp, int ld, char* lds){
  const int tid = threadIdx.x;
  const int wid = tid >> 6;
#pragma unroll
  for (int q = 0; q < R/64; ++q){
    const int slot = q*256 + tid;            // = r*4 + unit
    const int r = slot >> 2, gi = slot & 3;
    const int u = gi ^ swz4(r);
    const unsigned short* ga = gp + r*ld + u*8;
    char* lb = lds + (q*256 + wid*64)*16;    // wave-uniform LDS base
    __builtin_amdgcn_global_load_lds(
        (__attribute__((address_space(1))) void*)ga,
        (__attribute__((address_space(3))) void*)lb, 16, 0, 0);
  }
}

__device__ __forceinline__ s16x8 ldsfrag(const char* lds, int r, int g){
  return *(const s16x8*)(lds + r*64 + ((g ^ swz4(r)) << 4));
}

// ---------------------------------------------------------------------------
// K0w: W fp32 -> bf16.
// ---------------------------------------------------------------------------
__global__ __launch_bounds__(256) void k0_w(
    const float* __restrict__ w, unsigned short* __restrict__ wb)
{
  const int i = blockIdx.x*256 + threadIdx.x;   // 16384 float4s
  float4 v = *(const float4*)(w + (size_t)i*4);
  uint2 h = {cvtpk(v.x, v.y), cvtpk(v.z, v.w)};
  *(uint2*)(wb + (size_t)i*4) = h;
}

// ---------------------------------------------------------------------------
// K0t2t (big path): r10's fused transpose+xb16, but TWO c-tiles per block
// with all 8 float4 loads issued before any barrier (2x MLP, 1.5 barriers
// per tile vs 2) and grid 3136 (TLP preserved — r11's 896-block collapse
// was the occupancy killer). Phase logic/store patterns identical to r10.
// ---------------------------------------------------------------------------
template<int M>
__global__ __launch_bounds__(256) void k0_t2t(
    const float* __restrict__ x, unsigned short* __restrict__ xt,
    unsigned short* __restrict__ xb16)
{
  __shared__ float T[64][65];
  const int tid = threadIdx.x;
  const int n0 = blockIdx.x*64, c0b = blockIdx.y*128, b = blockIdx.z;
  const int cr = tid >> 4, nc = (tid & 15)*4;  // phase-1 geometry (r10)
  const int nn = tid >> 2, cq = tid & 3;       // phase-2 geometry (r10)

  float4 v[2][4];
#pragma unroll
  for (int t = 0; t < 2; ++t)
#pragma unroll
    for (int q = 0; q < 4; ++q)
      v[t][q] = *(const float4*)(x + ((size_t)b*C_ + c0b + t*64 + q*16 + cr)*N_ + n0 + nc);

#pragma unroll
  for (int t = 0; t < 2; ++t){
    const int c0 = c0b + t*64;
    if (t) __syncthreads();                    // protect T from overwrite
#pragma unroll
    for (int q = 0; q < 4; ++q){
      const int r = q*16 + cr;
      T[r][nc+0] = v[t][q].x; T[r][nc+1] = v[t][q].y;
      T[r][nc+2] = v[t][q].z; T[r][nc+3] = v[t][q].w;
      if (M){
        uint2 hh = {cvtpk(v[t][q].x, v[t][q].y), cvtpk(v[t][q].z, v[t][q].w)};
        *(uint2*)(xb16 + ((size_t)b*C_ + c0 + r)*N_ + n0 + nc) = hh;
      }
    }
    __syncthreads();
    unsigned h[8];
#pragma unroll
    for (int j = 0; j < 8; ++j)
      h[j] = cvtpk(T[cq*16 + 2*j][nn], T[cq*16 + 2*j + 1][nn]);
    unsigned short* dst = xt + ((size_t)b*N_ + n0 + nn)*C_ + c0 + cq*16;
    *(uint4*)dst       = (uint4){h[0], h[1], h[2], h[3]};
    *(uint4*)(dst + 8) = (uint4){h[4], h[5], h[6], h[7]};
  }
}

// ---------------------------------------------------------------------------
// K0t: fused transpose + optional xb16 (EXACT round-10 version — proven).
// Used only on the small-ws fallback path (M=0).
// ---------------------------------------------------------------------------
template<int M>
__global__ __launch_bounds__(256) void k0_t(
    const float* __restrict__ x, unsigned short* __restrict__ xt,
    unsigned short* __restrict__ xb16)
{
  __shared__ float T[64][65];
  const int tid = threadIdx.x;
  const int n0 = blockIdx.x*64, c0 = blockIdx.y*64, b = blockIdx.z;
  const float* xb = x + ((size_t)b*C_ + c0)*N_ + n0;
#pragma unroll
  for (int q = 0; q < 4; ++q){
    const int cr = q*16 + (tid >> 4), nc = (tid & 15)*4;
    float4 v = *(const float4*)(xb + (size_t)cr*N_ + nc);
    T[cr][nc+0] = v.x; T[cr][nc+1] = v.y; T[cr][nc+2] = v.z; T[cr][nc+3] = v.w;
    if (M){
      uint2 hh = {cvtpk(v.x, v.y), cvtpk(v.z, v.w)};
      *(uint2*)(xb16 + ((size_t)b*C_ + c0 + cr)*N_ + n0 + nc) = hh;
    }
  }
  __syncthreads();
  const int nn = tid >> 2, cq = tid & 3;
  unsigned h[8];
#pragma unroll
  for (int j = 0; j < 8; ++j)
    h[j] = cvtpk(T[cq*16 + 2*j][nn], T[cq*16 + 2*j + 1][nn]);
  unsigned short* dst = xt + ((size_t)b*N_ + n0 + nn)*C_ + c0 + cq*16;
  *(uint4*)dst       = (uint4){h[0], h[1], h[2], h[3]};
  *(uint4*)(dst + 8) = (uint4){h[4], h[5], h[6], h[7]};
}

// ---------------------------------------------------------------------------
// K1: qk = elu(W.x + b)+1.  MFMA GEMM M=256(o) x BN=64(n) x K=256(c).
// Pure global_load_lds staging. Waves 0-1 -> q half stored qt[b][n][d];
// waves 2-3 -> k half kbuf[b][d][n].  (EXACT round-7 version — proven.)
// ---------------------------------------------------------------------------
__global__ __launch_bounds__(256) void k1_qk(
    const unsigned short* __restrict__ xt, const unsigned short* __restrict__ wb,
    const float* __restrict__ bias,
    unsigned short* __restrict__ kbuf, unsigned short* __restrict__ qt)
{
  __shared__ __align__(16) char Al[256*64];  // [256 o][32 c] bf16, swizzled
  __shared__ __align__(16) char Bl[64*64];   // [64 n][32 c]  bf16, swizzled
  const int tid = threadIdx.x, lane = tid & 63, wid = tid >> 6;
  const int n0 = blockIdx.x * 64;
  const int b  = blockIdx.y;
  const unsigned short* xtb = xt + ((size_t)b*N_ + n0)*C_;
  const int wo = wid*64;
  f32x4 acc[4][4] = {};

  for (int k0 = 0; k0 < C_; k0 += 32){
    __syncthreads();
    stage_glds<256>(wb + k0, C_, Al);
    stage_glds<64>(xtb + k0, C_, Bl);
    __syncthreads();
    s16x8 af[4], bv4[4];
#pragma unroll
    for (int m = 0; m < 4; ++m)  af[m]  = ldsfrag(Al, wo + m*16 + (lane & 15), lane >> 4);
#pragma unroll
    for (int nf = 0; nf < 4; ++nf) bv4[nf] = ldsfrag(Bl, nf*16 + (lane & 15), lane >> 4);
#pragma unroll
    for (int m = 0; m < 4; ++m)
#pragma unroll
      for (int nf = 0; nf < 4; ++nf)
        acc[m][nf] = __builtin_amdgcn_mfma_f32_16x16x32_bf16(af[m], bv4[nf], acc[m][nf], 0, 0, 0);
  }

  const int col = lane & 15, rg = lane >> 4;
  if (wid < 2){
    // q half -> qt[b][n][d]
#pragma unroll
    for (int m = 0; m < 4; ++m){
      const int db = wo + m*16 + rg*4;
      const float b0 = bias[db], b1 = bias[db+1], b2 = bias[db+2], b3 = bias[db+3];
#pragma unroll
      for (int nf = 0; nf < 4; ++nf){
        const int n = n0 + nf*16 + col;
        f32x4 a = acc[m][nf];
        uint2 hv = {cvtpk(elu1(a[0]+b0), elu1(a[1]+b1)),
                    cvtpk(elu1(a[2]+b2), elu1(a[3]+b3))};
        *(uint2*)(qt + ((size_t)b*N_ + n)*D_ + db) = hv;
      }
    }
  } else {
    // k half -> kbuf[b][d][n]
#pragma unroll
    for (int m = 0; m < 4; ++m)
#pragma unroll
      for (int j = 0; j < 4; ++j){
        const int d = wo - 128 + m*16 + rg*4 + j;
        const float bb = bias[128 + d];
#pragma unroll
        for (int nf = 0; nf < 4; ++nf){
          const int n = n0 + nf*16 + col;
          kbuf[((size_t)b*D_ + d)*N_ + n] = f2bf(elu1(acc[m][nf][j] + bb));
        }
      }
  }
}

// ---------------------------------------------------------------------------
// K2: kv partials = sum_n k[d][n]*x[c][n] over K-split. M=128(d) x BN=256(c)
// x K=448(n). 512 threads / 8 waves. Partials stored [c][d]. Fuses kmean.
// M=0: B from x fp32 + cvt_pk (r7 proven). M=1: B pure DMA from xb16.
// (EXACT round-10 version — proven.)
// ---------------------------------------------------------------------------
template<int M>
__global__ __launch_bounds__(512) void k2_kv(
    const unsigned short* __restrict__ kbuf, const float* __restrict__ x,
    const unsigned short* __restrict__ xb16,
    unsigned short* __restrict__ kvp, float* __restrict__ kmp)
{
  __shared__ __align__(16) char Al[128*64];  // [128 d][32 n]
  __shared__ __align__(16) char Bl[256*64];  // [256 c][32 n]
  const int tid = threadIdx.x, lane = tid & 63, wid = tid >> 6;  // 8 waves
  const int ks = blockIdx.x;
  const int b  = blockIdx.y;
  const unsigned short* kb = kbuf + (size_t)b*D_*N_ + ks*KRANGE;
  const float* xb = x + (size_t)b*C_*N_ + ks*KRANGE;
  const unsigned short* xbb = xb16 + (size_t)b*C_*N_ + ks*KRANGE;
  const int wd = (wid >> 2)*64, wc = (wid & 3)*64;
  f32x4 acc[4][4] = {};
  float kms = 0.f;
  const int sr = tid >> 2, sg = tid & 3;     // staging/kms row & unit

  for (int t = 0; t < KRANGE/32; ++t){
    __syncthreads();
    // A: 128 rows x 4 units = 512 slots, one global_load_lds per thread
    {
      const int u = sg ^ swz4(sr);
      const unsigned short* ga = kb + (size_t)sr*N_ + t*32 + u*8;
      char* lb = Al + (wid*64)*16;           // wave-uniform base; unit = tid
      __builtin_amdgcn_global_load_lds(
          (__attribute__((address_space(1))) void*)ga,
          (__attribute__((address_space(3))) void*)lb, 16, 0, 0);
    }
    if (M){
      // B: 256 rows x 4 units = 1024 slots, two DMAs per thread
#pragma unroll
      for (int q = 0; q < 2; ++q){
        const int slot = q*512 + tid;
        const int r = slot >> 2, gi = slot & 3;
        const int u = gi ^ swz4(r);
        const unsigned short* ga = xbb + (size_t)r*N_ + t*32 + u*8;
        char* lb = Bl + (q*512 + wid*64)*16;
        __builtin_amdgcn_global_load_lds(
            (__attribute__((address_space(1))) void*)ga,
            (__attribute__((address_space(3))) void*)lb, 16, 0, 0);
      }
    } else {
      // B: x[c][n] fp32 -> bf16 (cvt_pk); 256 rows x 32 n, 16 elems/thread
#pragma unroll
      for (int q = 0; q < 4; ++q){
        int idx = q*512 + tid;                 // 0..2047
        int cc = idx >> 3, n4 = (idx & 7)*4;
        float4 v = *(const float4*)(xb + (size_t)cc*N_ + t*32 + n4);
        uint2 h = {cvtpk(v.x, v.y), cvtpk(v.z, v.w)};
        *(uint2*)(Bl + cc*64 + ((n4*2) ^ (swz4(cc) << 4))) = h;
      }
    }
    __syncthreads();
    s16x8 af[4], bv[4];
#pragma unroll
    for (int m = 0; m < 4; ++m)  af[m] = ldsfrag(Al, wd + m*16 + (lane & 15), lane >> 4);
#pragma unroll
    for (int cf = 0; cf < 4; ++cf) bv[cf] = ldsfrag(Bl, wc + cf*16 + (lane & 15), lane >> 4);
#pragma unroll
    for (int m = 0; m < 4; ++m)
#pragma unroll
      for (int cf = 0; cf < 4; ++cf)
        acc[m][cf] = __builtin_amdgcn_mfma_f32_16x16x32_bf16(af[m], bv[cf], acc[m][cf], 0, 0, 0);
    // kmean partial: thread (sr, sg) sums unit sg of k-row sr (8 bf16)
    {
      uint2 u = *(const uint2*)(Al + sr*64 + ((sg ^ swz4(sr)) << 4));
      uint2 u2 = *(const uint2*)(Al + sr*64 + ((sg ^ swz4(sr)) << 4) + 8);
      const unsigned ua[4] = {u.x, u.y, u2.x, u2.y};
#pragma unroll
      for (int i = 0; i < 4; ++i){
        kms += bf2f((unsigned short)(ua[i] & 0xffffu));
        kms += bf2f((unsigned short)(ua[i] >> 16));
      }
    }
  }

  kms += __shfl_xor(kms, 1);
  kms += __shfl_xor(kms, 2);
  if ((tid & 3) == 0) kmp[((size_t)b*KSPLIT + ks)*D_ + sr] = kms;

  const int col = lane & 15, rg = lane >> 4;
#pragma unroll
  for (int m = 0; m < 4; ++m){
    const int d0 = wd + m*16 + rg*4;
#pragma unroll
    for (int cf = 0; cf < 4; ++cf){
      const int c = wc + cf*16 + col;
      ushort4 hv = {f2bf(acc[m][cf][0]), f2bf(acc[m][cf][1]),
                    f2bf(acc[m][cf][2]), f2bf(acc[m][cf][3])};
      *(ushort4*)(kvp + (((size_t)b*KSPLIT + ks)*C_ + c)*D_ + d0) = hv;
    }
  }
}

// ---------------------------------------------------------------------------
// KR: kvt[b][c][d] = (1/N) * sum_ks kvp[b][ks][c][d]; km[b][d] from kmp.
// (EXACT round-7 version — proven.)
// ---------------------------------------------------------------------------
__global__ __launch_bounds__(256) void kr_reduce(
    const unsigned short* __restrict__ kvp, const float* __restrict__ kmp,
    unsigned short* __restrict__ kvt, float* __restrict__ km)
{
  const int tid = threadIdx.x;
  const int bx = blockIdx.x, b = blockIdx.y;
  const float sc = 1.0f/(float)N_;
#pragma unroll
  for (int it = 0; it < 2; ++it){
    const int idx = (bx*2 + it)*256 + tid;      // 0..4095
    const int c = idx >> 4, dq = (idx & 15)*8;
    float s[8] = {};
    for (int ks = 0; ks < KSPLIT; ++ks){
      u16x8 v = *(const u16x8*)(kvp + (((size_t)b*KSPLIT + ks)*C_ + c)*D_ + dq);
#pragma unroll
      for (int i = 0; i < 8; ++i) s[i] += bf2f(v[i]);
    }
    u16x8 h;
#pragma unroll
    for (int i = 0; i < 8; ++i) h[i] = f2bf(s[i]*sc);
    *(u16x8*)(kvt + ((size_t)b*C_ + c)*D_ + dq) = h;
  }
  if (bx == 0 && tid < D_){
    float s = 0.f;
    for (int ks = 0; ks < KSPLIT; ++ks) s += kmp[((size_t)b*KSPLIT + ks)*D_ + tid];
    km[b*D_ + tid] = s*sc;
  }
}

// ---------------------------------------------------------------------------
// K3: attn[c][n] = (sum_d kvt[c][d]*qt[n][d]) / (q.km + 1e-6), bf16 out.
// (EXACT round-7 version — proven.)
// ---------------------------------------------------------------------------
__global__ __launch_bounds__(256) void k3_attn(
    const unsigned short* __restrict__ qt, const unsigned short* __restrict__ kvt,
    const float* __restrict__ km, unsigned short* __restrict__ attn)
{
  __shared__ __align__(16) char SM[256*64 + 64*64];  // 20KB
  char* Al = SM;                                 // [256 c][32 d] (16KB)
  char* Bl = SM + 256*64;                        // [64 n][32 d]  (4KB)
  unsigned short* P = (unsigned short*)SM;       // [128][72] bf16 (18KB overlay)
  __shared__ float kms[128];
  __shared__ float dens[64];
  const int tid = threadIdx.x, lane = tid & 63, wid = tid >> 6;
  const int n0 = blockIdx.x * 64;
  const int b  = blockIdx.y;
  if (tid < 128) kms[tid] = km[b*D_ + tid];
  const unsigned short* kvb = kvt + (size_t)b*C_*D_;
  const unsigned short* qtb = qt + ((size_t)b*N_ + n0)*D_;
  const int wc = wid*64;
  f32x4 acc[4][4] = {};
  float den = 0.f;

  for (int k0 = 0; k0 < D_; k0 += 32){
    __syncthreads();
    stage_glds<256>(kvb + k0, D_, Al);
    stage_glds<64>(qtb + k0, D_, Bl);
    __syncthreads();
    s16x8 af[4], bv4[4];
#pragma unroll
    for (int m = 0; m < 4; ++m)  af[m]  = ldsfrag(Al, wc + m*16 + (lane & 15), lane >> 4);
#pragma unroll
    for (int nf = 0; nf < 4; ++nf) bv4[nf] = ldsfrag(Bl, nf*16 + (lane & 15), lane >> 4);
#pragma unroll
    for (int m = 0; m < 4; ++m)
#pragma unroll
      for (int nf = 0; nf < 4; ++nf)
        acc[m][nf] = __builtin_amdgcn_mfma_f32_16x16x32_bf16(af[m], bv4[nf], acc[m][nf], 0, 0, 0);
    {
      const int nr = tid >> 2, g = tid & 3;
      uint4 u = *(const uint4*)(Bl + nr*64 + ((g ^ swz4(nr)) << 4));
      const float* kp = kms + k0 + g*8;
      const unsigned ua[4] = {u.x, u.y, u.z, u.w};
#pragma unroll
      for (int i = 0; i < 4; ++i){
        den += bf2f((unsigned short)(ua[i] & 0xffffu)) * kp[i*2];
        den += bf2f((unsigned short)(ua[i] >> 16))     * kp[i*2 + 1];
      }
    }
  }
  den += __shfl_xor(den, 1);
  den += __shfl_xor(den, 2);
  if ((tid & 3) == 0) dens[tid >> 2] = den;
  __syncthreads();   // GEMM LDS reads done + dens visible

  const int col = lane & 15, rg = lane >> 4;
  float rdv[4];
#pragma unroll
  for (int nf = 0; nf < 4; ++nf)
    rdv[nf] = 1.0f / (dens[nf*16 + col] + 1e-6f);

#pragma unroll
  for (int h = 0; h < 2; ++h){
    if ((wid >> 1) == h){
      const int lc = wc - h*128;   // 0 or 64
#pragma unroll
      for (int m = 0; m < 4; ++m)
#pragma unroll
        for (int nf = 0; nf < 4; ++nf)
#pragma unroll
          for (int j = 0; j < 4; ++j)
            P[(lc + m*16 + rg*4 + j)*72 + (nf*16 + col)] = f2bf(acc[m][nf][j] * rdv[nf]);
    }
    __syncthreads();
#pragma unroll
    for (int p = 0; p < 4; ++p){
      const int c = (tid >> 3) + p*32, ch = tid & 7;
      u16x8 v = *(const u16x8*)(P + c*72 + ch*8);
      *(u16x8*)(attn + ((size_t)b*C_ + h*128 + c)*N_ + n0 + ch*8) = v;
    }
    __syncthreads();
  }
}

// ---------------------------------------------------------------------------
// K4: out = attn + depthwise3x3(x) + pe_b. Plane per block, 4-wide along w,
// zero-padded top/bottom LDS rows. M=0: x fp32 (r7 proven). M=1: x from xb16.
// (EXACT round-10 version — proven.)
// ---------------------------------------------------------------------------
template<int M>
__global__ __launch_bounds__(256) void k4_pe(
    const float* __restrict__ x, const unsigned short* __restrict__ xb16,
    const unsigned short* __restrict__ attn,
    const float* __restrict__ pw, const float* __restrict__ pb,
    float* __restrict__ out)
{
  __shared__ float xs_raw[58*56 + 8];
  float* xs = xs_raw + 4;          // slack so xs[-1] stays in-bounds
  const int tid = threadIdx.x;
  const int ch = blockIdx.x, b = blockIdx.y;
  if (tid < 14)      ((float4*)xs)[tid] = (float4){0.f,0.f,0.f,0.f};        // pad row 0
  else if (tid < 28) ((float4*)xs)[784 + tid] = (float4){0.f,0.f,0.f,0.f};  // pad row 57
  if (M){
    const unsigned short* xp = xb16 + ((size_t)b*C_ + ch)*N_;
    for (int i = tid; i < 392; i += 256){
      u16x8 v = ((const u16x8*)xp)[i];
      float4 f0 = {bf2f(v[0]), bf2f(v[1]), bf2f(v[2]), bf2f(v[3])};
      float4 f1 = {bf2f(v[4]), bf2f(v[5]), bf2f(v[6]), bf2f(v[7])};
      ((float4*)xs)[14 + 2*i]     = f0;
      ((float4*)xs)[14 + 2*i + 1] = f1;
    }
  } else {
    const float* xp = x + ((size_t)b*C_ + ch)*N_;
    for (int i = tid; i < 784; i += 256)
      ((float4*)xs)[14 + i] = ((const float4*)xp)[i];
  }
  const float* wp = pw + ch*9;
  float wgt[9];
#pragma unroll
  for (int i = 0; i < 9; ++i) wgt[i] = wp[i];
  const float bias = pb[ch];
  __syncthreads();
  const unsigned short* ap = attn + ((size_t)b*C_ + ch)*N_;
  float* op = out + ((size_t)b*C_ + ch)*N_;
  for (int u = tid; u < 784; u += 256) {
    const int row = u / 14, g = u - row*14;     // output row, float4 group
    float o0 = bias, o1 = bias, o2 = bias, o3 = bias;
#pragma unroll
    for (int rr = 0; rr < 3; ++rr){
      const float* rp = xs + (row + rr)*56 + g*4;   // padded rows row..row+2
      float4 cv = *(const float4*)rp;
      float lf = (g > 0)  ? rp[-1] : 0.f;
      float rt = (g < 13) ? rp[4]  : 0.f;
      const float wl = wgt[rr*3], wc_ = wgt[rr*3+1], wr = wgt[rr*3+2];
      o0 += wl*lf   + wc_*cv.x + wr*cv.y;
      o1 += wl*cv.x + wc_*cv.y + wr*cv.z;
      o2 += wl*cv.y + wc_*cv.z + wr*cv.w;
      o3 += wl*cv.z + wc_*cv.w + wr*rt;
    }
    ushort4 av = *(const ushort4*)(ap + u*4);
    float4 ov = {o0 + bf2f(av.x), o1 + bf2f(av.y), o2 + bf2f(av.z), o3 + bf2f(av.w)};
    *(float4*)(op + u*4) = ov;
  }
}

extern "C" void kernel_launch(void* const* d_in, const int* in_sizes, int n_in,
                              void* d_out, int out_size, void* d_ws, size_t ws_size,
                              hipStream_t stream) {
  (void)in_sizes; (void)n_in; (void)out_size;
  const float* x   = (const float*)d_in[0];
  const float* qkw = (const float*)d_in[1];
  const float* qkb = (const float*)d_in[2];
  const float* pew = (const float*)d_in[3];
  const float* peb = (const float*)d_in[4];
  float* out = (float*)d_out;

  // Base ws layout (104.9 MB, round-7 proven). Optional xb16 slot appended
  // (51.4 MB) used only when ws_size is large enough (path A).
  unsigned short* xts  = (unsigned short*)d_ws;                 // [B][N][C] bf16
  unsigned short* kbuf = xts + (size_t)B_*N_*C_;                // [B][128][N] bf16
  unsigned short* qt   = kbuf + (size_t)B_*D_*N_;               // [B][N][128] bf16
  unsigned short* kvt  = qt   + (size_t)B_*N_*D_;               // [B][256][128] bf16
  float* km  = (float*)(kvt + (size_t)B_*C_*D_);                // [B][128] f32
  unsigned short* xb16 = (unsigned short*)(km + (size_t)B_*D_); // [B][C][N] bf16 (path A)
  unsigned short* wb   = kvt;                                   // [256][256] bf16 (alias)
  unsigned short* kvp  = xts;                                   // [B][7][256][128] bf16 (alias)
  float* kmp = (float*)(kvp + (size_t)B_*KSPLIT*C_*D_);         // [B][7][128] f32 (in xt slot)
  unsigned short* attn = xts;                                   // [B][256][N] bf16 (alias)

  const size_t need_a = ((size_t)B_*N_*C_ + (size_t)B_*D_*N_ + (size_t)B_*N_*D_
                       + (size_t)B_*C_*D_)*2 + (size_t)B_*D_*4
                       + (size_t)B_*C_*N_*2;    // = 156,254,208 bytes
  const bool big = ws_size >= need_a;

  k0_w<<<dim3(64), 256, 0, stream>>>(qkw, wb);
  if (big){
    k0_t2t<1><<<dim3(N_/64, C_/128, B_), 256, 0, stream>>>(x, xts, xb16);
  } else {
    k0_t<0><<<dim3(N_/64, C_/64, B_), 256, 0, stream>>>(x, xts, xb16);
  }
  k1_qk<<<dim3(N_/64, B_), 256, 0, stream>>>(xts, wb, qkb, kbuf, qt);
  if (big){
    k2_kv<1><<<dim3(KSPLIT, B_), 512, 0, stream>>>(kbuf, x, xb16, kvp, kmp);
  } else {
    k2_kv<0><<<dim3(KSPLIT, B_), 512, 0, stream>>>(kbuf, x, xb16, kvp, kmp);
  }
  kr_reduce<<<dim3(8, B_), 256, 0, stream>>>(kvp, kmp, kvt, km);
  k3_attn<<<dim3(N_/64, B_), 256, 0, stream>>>(qt, kvt, km, attn);
  if (big){
    k4_pe<1><<<dim3(C_, B_), 256, 0, stream>>>(x, xb16, attn, pew, peb, out);
  } else {
    k4_pe<0><<<dim3(C_, B_), 256, 0, stream>>>(x, xb16, attn, pew, peb, out);
  }
}

// Round 15
// 153.269 us; speedup vs baseline: 1.2335x; 1.0810x over previous
//
#include <hip/hip_runtime.h>

#define B_ 32
#define C_ 256
#define D_ 128
#define HH 56
#define WW 56
#define N_ 3136
#define KSPLIT 7
#define KRANGE 448   // n per K-split in k2: 14 steps of 32

typedef float f32x4 __attribute__((ext_vector_type(4)));
typedef short s16x8 __attribute__((ext_vector_type(8)));
typedef unsigned short u16x8 __attribute__((ext_vector_type(8)));

// Row swizzle for [R][32-bf16] LDS tiles (64B rows = 4x16B units).
__device__ __forceinline__ int swz4(int r){
  return (r & 3) ^ (((r >> 2) & 1) << 1) ^ ((r >> 3) & 1);
}
__device__ __forceinline__ unsigned short f2bf(float f){
  unsigned u = __float_as_uint(f);
  u += 0x7fffu + ((u >> 16) & 1u);           // RNE
  return (unsigned short)(u >> 16);
}
__device__ __forceinline__ float bf2f(unsigned short h){
  return __uint_as_float(((unsigned)h) << 16);
}
__device__ __forceinline__ float elu1(float v){
  return v > 0.f ? v + 1.f : __expf(v);      // elu(v)+1
}
// HW packed f32x2 -> bf16x2 (RNE), 1 instr for 2 values.
__device__ __forceinline__ unsigned cvtpk(float lo, float hi){
  unsigned r;
  asm("v_cvt_pk_bf16_f32 %0, %1, %2" : "=v"(r) : "v"(lo), "v"(hi));
  return r;
}

// Stage [R rows][32 bf16] from bf16 global (pitch ld) into swizzled LDS via
// global_load_lds: dest is lane-linear, swizzle pre-applied on global source.
// 256-thread variant.
template<int R>
__device__ __forceinline__ void stage_glds(const unsigned short* gp, int ld, char* lds){
  const int tid = threadIdx.x;
  const int wid = tid >> 6;
#pragma unroll
  for (int q = 0; q < R/64; ++q){
    const int slot = q*256 + tid;            // = r*4 + unit
    const int r = slot >> 2, gi = slot & 3;
    const int u = gi ^ swz4(r);
    const unsigned short* ga = gp + r*ld + u*8;
    char* lb = lds + (q*256 + wid*64)*16;    // wave-uniform LDS base
    __builtin_amdgcn_global_load_lds(
        (__attribute__((address_space(1))) void*)ga,
        (__attribute__((address_space(3))) void*)lb, 16, 0, 0);
  }
}

__device__ __forceinline__ s16x8 ldsfrag(const char* lds, int r, int g){
  return *(const s16x8*)(lds + r*64 + ((g ^ swz4(r)) << 4));
}

// ---------------------------------------------------------------------------
// K0w: W fp32 -> bf16.
// ---------------------------------------------------------------------------
__global__ __launch_bounds__(256) void k0_w(
    const float* __restrict__ w, unsigned short* __restrict__ wb)
{
  const int i = blockIdx.x*256 + threadIdx.x;   // 16384 float4s
  float4 v = *(const float4*)(w + (size_t)i*4);
  uint2 h = {cvtpk(v.x, v.y), cvtpk(v.z, v.w)};
  *(uint2*)(wb + (size_t)i*4) = h;
}

// ---------------------------------------------------------------------------
// K1: qk = elu(W.x + b)+1.  MFMA GEMM M=256(o) x BN=64(n) x K=256(c).
// A (W bf16) via global_load_lds; B staged from x fp32 with IN-KERNEL
// transpose scatter into swizzled Bl[n][c] (round-2/3-proven pattern —
// correctness-verified; reinstated to DELETE the 58us k0_t transpose kernel
// that 4 structural rewrites failed to speed up). x loads issued before the
// barrier to overlap the previous iteration's MFMA phase.
// Waves 0-1 -> q half stored qt[b][n][d]; waves 2-3 -> k half kbuf[b][d][n].
// ---------------------------------------------------------------------------
__global__ __launch_bounds__(256) void k1_qk(
    const float* __restrict__ x, const unsigned short* __restrict__ wb,
    const float* __restrict__ bias,
    unsigned short* __restrict__ kbuf, unsigned short* __restrict__ qt)
{
  __shared__ __align__(16) char Al[256*64];  // [256 o][32 c] bf16, swizzled
  __shared__ __align__(16) char Bl[64*64];   // [64 n][32 c]  bf16, swizzled
  const int tid = threadIdx.x, lane = tid & 63, wid = tid >> 6;
  const int n0 = blockIdx.x * 64;
  const int b  = blockIdx.y;
  const float* xb = x + (size_t)b*C_*N_;
  const int wo = wid*64;
  f32x4 acc[4][4] = {};

  for (int k0 = 0; k0 < C_; k0 += 32){
    // B tile loads (x fp32, coalesced): issue BEFORE barrier to overlap MFMA
    float4 xv[2];
    int cc[2], nn[2];
#pragma unroll
    for (int q = 0; q < 2; ++q){
      const int idx = q*256 + tid;
      cc[q] = idx >> 4;            // 0..31 (c within K-step)
      nn[q] = (idx & 15)*4;        // 0..60 (n within tile)
      xv[q] = *(const float4*)(xb + (size_t)(k0 + cc[q])*N_ + n0 + nn[q]);
    }
    __syncthreads();               // previous iteration's LDS reads done
    stage_glds<256>(wb + k0, C_, Al);
    // transpose scatter: Bl[n][c] bf16, swz4 row swizzle (r2-proven)
#pragma unroll
    for (int q = 0; q < 2; ++q){
      const float vv[4] = {xv[q].x, xv[q].y, xv[q].z, xv[q].w};
#pragma unroll
      for (int i = 0; i < 4; ++i){
        const int r = nn[q] + i;
        *(unsigned short*)(Bl + r*64 + ((cc[q]*2) ^ (swz4(r) << 4))) = f2bf(vv[i]);
      }
    }
    __syncthreads();               // DMA + scatter visible
    s16x8 af[4], bv4[4];
#pragma unroll
    for (int m = 0; m < 4; ++m)  af[m]  = ldsfrag(Al, wo + m*16 + (lane & 15), lane >> 4);
#pragma unroll
    for (int nf = 0; nf < 4; ++nf) bv4[nf] = ldsfrag(Bl, nf*16 + (lane & 15), lane >> 4);
#pragma unroll
    for (int m = 0; m < 4; ++m)
#pragma unroll
      for (int nf = 0; nf < 4; ++nf)
        acc[m][nf] = __builtin_amdgcn_mfma_f32_16x16x32_bf16(af[m], bv4[nf], acc[m][nf], 0, 0, 0);
  }

  const int col = lane & 15, rg = lane >> 4;
  if (wid < 2){
    // q half -> qt[b][n][d]
#pragma unroll
    for (int m = 0; m < 4; ++m){
      const int db = wo + m*16 + rg*4;
      const float b0 = bias[db], b1 = bias[db+1], b2 = bias[db+2], b3 = bias[db+3];
#pragma unroll
      for (int nf = 0; nf < 4; ++nf){
        const int n = n0 + nf*16 + col;
        f32x4 a = acc[m][nf];
        uint2 hv = {cvtpk(elu1(a[0]+b0), elu1(a[1]+b1)),
                    cvtpk(elu1(a[2]+b2), elu1(a[3]+b3))};
        *(uint2*)(qt + ((size_t)b*N_ + n)*D_ + db) = hv;
      }
    }
  } else {
    // k half -> kbuf[b][d][n]
#pragma unroll
    for (int m = 0; m < 4; ++m)
#pragma unroll
      for (int j = 0; j < 4; ++j){
        const int d = wo - 128 + m*16 + rg*4 + j;
        const float bb = bias[128 + d];
#pragma unroll
        for (int nf = 0; nf < 4; ++nf){
          const int n = n0 + nf*16 + col;
          kbuf[((size_t)b*D_ + d)*N_ + n] = f2bf(elu1(acc[m][nf][j] + bb));
        }
      }
  }
}

// ---------------------------------------------------------------------------
// K2: kv partials = sum_n k[d][n]*x[c][n] over K-split. M=128(d) x BN=256(c)
// x K=448(n). 512 threads / 8 waves. Partials stored [c][d]. Fuses kmean.
// B from x fp32 + cvt_pk inline (EXACT round-7 proven path).
// ---------------------------------------------------------------------------
__global__ __launch_bounds__(512) void k2_kv(
    const unsigned short* __restrict__ kbuf, const float* __restrict__ x,
    unsigned short* __restrict__ kvp, float* __restrict__ kmp)
{
  __shared__ __align__(16) char Al[128*64];  // [128 d][32 n]
  __shared__ __align__(16) char Bl[256*64];  // [256 c][32 n]
  const int tid = threadIdx.x, lane = tid & 63, wid = tid >> 6;  // 8 waves
  const int ks = blockIdx.x;
  const int b  = blockIdx.y;
  const unsigned short* kb = kbuf + (size_t)b*D_*N_ + ks*KRANGE;
  const float* xb = x + (size_t)b*C_*N_ + ks*KRANGE;
  const int wd = (wid >> 2)*64, wc = (wid & 3)*64;
  f32x4 acc[4][4] = {};
  float kms = 0.f;
  const int sr = tid >> 2, sg = tid & 3;     // staging/kms row & unit

  for (int t = 0; t < KRANGE/32; ++t){
    __syncthreads();
    // A: 128 rows x 4 units = 512 slots, one global_load_lds per thread
    {
      const int u = sg ^ swz4(sr);
      const unsigned short* ga = kb + (size_t)sr*N_ + t*32 + u*8;
      char* lb = Al + (wid*64)*16;           // wave-uniform base; unit = tid
      __builtin_amdgcn_global_load_lds(
          (__attribute__((address_space(1))) void*)ga,
          (__attribute__((address_space(3))) void*)lb, 16, 0, 0);
    }
    // B: x[c][n] fp32 -> bf16 (cvt_pk); 256 rows x 32 n, 16 elems/thread
#pragma unroll
    for (int q = 0; q < 4; ++q){
      int idx = q*512 + tid;                 // 0..2047
      int cc = idx >> 3, n4 = (idx & 7)*4;
      float4 v = *(const float4*)(xb + (size_t)cc*N_ + t*32 + n4);
      uint2 h = {cvtpk(v.x, v.y), cvtpk(v.z, v.w)};
      *(uint2*)(Bl + cc*64 + ((n4*2) ^ (swz4(cc) << 4))) = h;
    }
    __syncthreads();
    s16x8 af[4], bv[4];
#pragma unroll
    for (int m = 0; m < 4; ++m)  af[m] = ldsfrag(Al, wd + m*16 + (lane & 15), lane >> 4);
#pragma unroll
    for (int cf = 0; cf < 4; ++cf) bv[cf] = ldsfrag(Bl, wc + cf*16 + (lane & 15), lane >> 4);
#pragma unroll
    for (int m = 0; m < 4; ++m)
#pragma unroll
      for (int cf = 0; cf < 4; ++cf)
        acc[m][cf] = __builtin_amdgcn_mfma_f32_16x16x32_bf16(af[m], bv[cf], acc[m][cf], 0, 0, 0);
    // kmean partial: thread (sr, sg) sums unit sg of k-row sr (8 bf16)
    {
      uint2 u = *(const uint2*)(Al + sr*64 + ((sg ^ swz4(sr)) << 4));
      uint2 u2 = *(const uint2*)(Al + sr*64 + ((sg ^ swz4(sr)) << 4) + 8);
      const unsigned ua[4] = {u.x, u.y, u2.x, u2.y};
#pragma unroll
      for (int i = 0; i < 4; ++i){
        kms += bf2f((unsigned short)(ua[i] & 0xffffu));
        kms += bf2f((unsigned short)(ua[i] >> 16));
      }
    }
  }

  kms += __shfl_xor(kms, 1);
  kms += __shfl_xor(kms, 2);
  if ((tid & 3) == 0) kmp[((size_t)b*KSPLIT + ks)*D_ + sr] = kms;

  const int col = lane & 15, rg = lane >> 4;
#pragma unroll
  for (int m = 0; m < 4; ++m){
    const int d0 = wd + m*16 + rg*4;
#pragma unroll
    for (int cf = 0; cf < 4; ++cf){
      const int c = wc + cf*16 + col;
      ushort4 hv = {f2bf(acc[m][cf][0]), f2bf(acc[m][cf][1]),
                    f2bf(acc[m][cf][2]), f2bf(acc[m][cf][3])};
      *(ushort4*)(kvp + (((size_t)b*KSPLIT + ks)*C_ + c)*D_ + d0) = hv;
    }
  }
}

// ---------------------------------------------------------------------------
// KR: kvt[b][c][d] = (1/N) * sum_ks kvp[b][ks][c][d]; km[b][d] from kmp.
// (EXACT round-7 version — proven.)
// ---------------------------------------------------------------------------
__global__ __launch_bounds__(256) void kr_reduce(
    const unsigned short* __restrict__ kvp, const float* __restrict__ kmp,
    unsigned short* __restrict__ kvt, float* __restrict__ km)
{
  const int tid = threadIdx.x;
  const int bx = blockIdx.x, b = blockIdx.y;
  const float sc = 1.0f/(float)N_;
#pragma unroll
  for (int it = 0; it < 2; ++it){
    const int idx = (bx*2 + it)*256 + tid;      // 0..4095
    const int c = idx >> 4, dq = (idx & 15)*8;
    float s[8] = {};
    for (int ks = 0; ks < KSPLIT; ++ks){
      u16x8 v = *(const u16x8*)(kvp + (((size_t)b*KSPLIT + ks)*C_ + c)*D_ + dq);
#pragma unroll
      for (int i = 0; i < 8; ++i) s[i] += bf2f(v[i]);
    }
    u16x8 h;
#pragma unroll
    for (int i = 0; i < 8; ++i) h[i] = f2bf(s[i]*sc);
    *(u16x8*)(kvt + ((size_t)b*C_ + c)*D_ + dq) = h;
  }
  if (bx == 0 && tid < D_){
    float s = 0.f;
    for (int ks = 0; ks < KSPLIT; ++ks) s += kmp[((size_t)b*KSPLIT + ks)*D_ + tid];
    km[b*D_ + tid] = s*sc;
  }
}

// ---------------------------------------------------------------------------
// K3: attn[c][n] = (sum_d kvt[c][d]*qt[n][d]) / (q.km + 1e-6), bf16 out.
// (EXACT round-7 version — proven.)
// ---------------------------------------------------------------------------
__global__ __launch_bounds__(256) void k3_attn(
    const unsigned short* __restrict__ qt, const unsigned short* __restrict__ kvt,
    const float* __restrict__ km, unsigned short* __restrict__ attn)
{
  __shared__ __align__(16) char SM[256*64 + 64*64];  // 20KB
  char* Al = SM;                                 // [256 c][32 d] (16KB)
  char* Bl = SM + 256*64;                        // [64 n][32 d]  (4KB)
  unsigned short* P = (unsigned short*)SM;       // [128][72] bf16 (18KB overlay)
  __shared__ float kms[128];
  __shared__ float dens[64];
  const int tid = threadIdx.x, lane = tid & 63, wid = tid >> 6;
  const int n0 = blockIdx.x * 64;
  const int b  = blockIdx.y;
  if (tid < 128) kms[tid] = km[b*D_ + tid];
  const unsigned short* kvb = kvt + (size_t)b*C_*D_;
  const unsigned short* qtb = qt + ((size_t)b*N_ + n0)*D_;
  const int wc = wid*64;
  f32x4 acc[4][4] = {};
  float den = 0.f;

  for (int k0 = 0; k0 < D_; k0 += 32){
    __syncthreads();
    stage_glds<256>(kvb + k0, D_, Al);
    stage_glds<64>(qtb + k0, D_, Bl);
    __syncthreads();
    s16x8 af[4], bv4[4];
#pragma unroll
    for (int m = 0; m < 4; ++m)  af[m]  = ldsfrag(Al, wc + m*16 + (lane & 15), lane >> 4);
#pragma unroll
    for (int nf = 0; nf < 4; ++nf) bv4[nf] = ldsfrag(Bl, nf*16 + (lane & 15), lane >> 4);
#pragma unroll
    for (int m = 0; m < 4; ++m)
#pragma unroll
      for (int nf = 0; nf < 4; ++nf)
        acc[m][nf] = __builtin_amdgcn_mfma_f32_16x16x32_bf16(af[m], bv4[nf], acc[m][nf], 0, 0, 0);
    {
      const int nr = tid >> 2, g = tid & 3;
      uint4 u = *(const uint4*)(Bl + nr*64 + ((g ^ swz4(nr)) << 4));
      const float* kp = kms + k0 + g*8;
      const unsigned ua[4] = {u.x, u.y, u.z, u.w};
#pragma unroll
      for (int i = 0; i < 4; ++i){
        den += bf2f((unsigned short)(ua[i] & 0xffffu)) * kp[i*2];
        den += bf2f((unsigned short)(ua[i] >> 16))     * kp[i*2 + 1];
      }
    }
  }
  den += __shfl_xor(den, 1);
  den += __shfl_xor(den, 2);
  if ((tid & 3) == 0) dens[tid >> 2] = den;
  __syncthreads();   // GEMM LDS reads done + dens visible

  const int col = lane & 15, rg = lane >> 4;
  float rdv[4];
#pragma unroll
  for (int nf = 0; nf < 4; ++nf)
    rdv[nf] = 1.0f / (dens[nf*16 + col] + 1e-6f);

#pragma unroll
  for (int h = 0; h < 2; ++h){
    if ((wid >> 1) == h){
      const int lc = wc - h*128;   // 0 or 64
#pragma unroll
      for (int m = 0; m < 4; ++m)
#pragma unroll
        for (int nf = 0; nf < 4; ++nf)
#pragma unroll
          for (int j = 0; j < 4; ++j)
            P[(lc + m*16 + rg*4 + j)*72 + (nf*16 + col)] = f2bf(acc[m][nf][j] * rdv[nf]);
    }
    __syncthreads();
#pragma unroll
    for (int p = 0; p < 4; ++p){
      const int c = (tid >> 3) + p*32, ch = tid & 7;
      u16x8 v = *(const u16x8*)(P + c*72 + ch*8);
      *(u16x8*)(attn + ((size_t)b*C_ + h*128 + c)*N_ + n0 + ch*8) = v;
    }
    __syncthreads();
  }
}

// ---------------------------------------------------------------------------
// K4: out = attn + depthwise3x3(x) + pe_b. Plane per block, 4-wide along w,
// zero-padded top/bottom LDS rows. x fp32 (EXACT round-7 proven path).
// ---------------------------------------------------------------------------
__global__ __launch_bounds__(256) void k4_pe(
    const float* __restrict__ x, const unsigned short* __restrict__ attn,
    const float* __restrict__ pw, const float* __restrict__ pb,
    float* __restrict__ out)
{
  __shared__ float xs_raw[58*56 + 8];
  float* xs = xs_raw + 4;          // slack so xs[-1] stays in-bounds
  const int tid = threadIdx.x;
  const int ch = blockIdx.x, b = blockIdx.y;
  if (tid < 14)      ((float4*)xs)[tid] = (float4){0.f,0.f,0.f,0.f};        // pad row 0
  else if (tid < 28) ((float4*)xs)[784 + tid] = (float4){0.f,0.f,0.f,0.f};  // pad row 57
  const float* xp = x + ((size_t)b*C_ + ch)*N_;
  for (int i = tid; i < 784; i += 256)
    ((float4*)xs)[14 + i] = ((const float4*)xp)[i];
  const float* wp = pw + ch*9;
  float wgt[9];
#pragma unroll
  for (int i = 0; i < 9; ++i) wgt[i] = wp[i];
  const float bias = pb[ch];
  __syncthreads();
  const unsigned short* ap = attn + ((size_t)b*C_ + ch)*N_;
  float* op = out + ((size_t)b*C_ + ch)*N_;
  for (int u = tid; u < 784; u += 256) {
    const int row = u / 14, g = u - row*14;     // output row, float4 group
    float o0 = bias, o1 = bias, o2 = bias, o3 = bias;
#pragma unroll
    for (int rr = 0; rr < 3; ++rr){
      const float* rp = xs + (row + rr)*56 + g*4;   // padded rows row..row+2
      float4 cv = *(const float4*)rp;
      float lf = (g > 0)  ? rp[-1] : 0.f;
      float rt = (g < 13) ? rp[4]  : 0.f;
      const float wl = wgt[rr*3], wc_ = wgt[rr*3+1], wr = wgt[rr*3+2];
      o0 += wl*lf   + wc_*cv.x + wr*cv.y;
      o1 += wl*cv.x + wc_*cv.y + wr*cv.z;
      o2 += wl*cv.y + wc_*cv.z + wr*cv.w;
      o3 += wl*cv.z + wc_*cv.w + wr*rt;
    }
    ushort4 av = *(const ushort4*)(ap + u*4);
    float4 ov = {o0 + bf2f(av.x), o1 + bf2f(av.y), o2 + bf2f(av.z), o3 + bf2f(av.w)};
    *(float4*)(op + u*4) = ov;
  }
}

extern "C" void kernel_launch(void* const* d_in, const int* in_sizes, int n_in,
                              void* d_out, int out_size, void* d_ws, size_t ws_size,
                              hipStream_t stream) {
  (void)in_sizes; (void)n_in; (void)out_size; (void)ws_size;
  const float* x   = (const float*)d_in[0];
  const float* qkw = (const float*)d_in[1];
  const float* qkb = (const float*)d_in[2];
  const float* pew = (const float*)d_in[3];
  const float* peb = (const float*)d_in[4];
  float* out = (float*)d_out;

  // ws layout (104.9 MB footprint, proven since round 7). The old xt slot
  // (51.4 MB) now only hosts kvp+kmp (k2->kr) then attn (k3->k4). kvt slot
  // hosts wb (k0w->k1) then kvt (kr->k3). No xt / xb16 anymore.
  unsigned short* slot0 = (unsigned short*)d_ws;                // 51.4 MB scratch
  unsigned short* kbuf = slot0 + (size_t)B_*N_*C_;              // [B][128][N] bf16
  unsigned short* qt   = kbuf + (size_t)B_*D_*N_;               // [B][N][128] bf16
  unsigned short* kvt  = qt   + (size_t)B_*N_*D_;               // [B][256][128] bf16
  float* km  = (float*)(kvt + (size_t)B_*C_*D_);                // [B][128] f32
  unsigned short* wb   = kvt;                                   // [256][256] bf16 (alias)
  unsigned short* kvp  = slot0;                                 // [B][7][256][128] bf16 (alias)
  float* kmp = (float*)(kvp + (size_t)B_*KSPLIT*C_*D_);         // [B][7][128] f32 (in slot0)
  unsigned short* attn = slot0;                                 // [B][256][N] bf16 (alias)

  k0_w     <<<dim3(64),          256, 0, stream>>>(qkw, wb);
  k1_qk    <<<dim3(N_/64, B_),   256, 0, stream>>>(x, wb, qkb, kbuf, qt);
  k2_kv    <<<dim3(KSPLIT, B_),  512, 0, stream>>>(kbuf, x, kvp, kmp);
  kr_reduce<<<dim3(8, B_),       256, 0, stream>>>(kvp, kmp, kvt, km);
  k3_attn  <<<dim3(N_/64, B_),   256, 0, stream>>>(qt, kvt, km, attn);
  k4_pe    <<<dim3(C_, B_),      256, 0, stream>>>(x, attn, pew, peb, out);
}

// Round 16
// 150.888 us; speedup vs baseline: 1.2530x; 1.0158x over previous
//
#include <hip/hip_runtime.h>

#define B_ 32
#define C_ 256
#define D_ 128
#define HH 56
#define WW 56
#define N_ 3136
#define KSPLIT 7
#define KRANGE 448   // n per K-split in k2: 14 steps of 32

typedef float f32x4 __attribute__((ext_vector_type(4)));
typedef short s16x8 __attribute__((ext_vector_type(8)));
typedef unsigned short u16x8 __attribute__((ext_vector_type(8)));

// Row swizzle for [R][32-bf16] LDS tiles (64B rows = 4x16B units).
__device__ __forceinline__ int swz4(int r){
  return (r & 3) ^ (((r >> 2) & 1) << 1) ^ ((r >> 3) & 1);
}
__device__ __forceinline__ unsigned short f2bf(float f){
  unsigned u = __float_as_uint(f);
  u += 0x7fffu + ((u >> 16) & 1u);           // RNE
  return (unsigned short)(u >> 16);
}
__device__ __forceinline__ float bf2f(unsigned short h){
  return __uint_as_float(((unsigned)h) << 16);
}
__device__ __forceinline__ float elu1(float v){
  return v > 0.f ? v + 1.f : __expf(v);      // elu(v)+1
}
// HW packed f32x2 -> bf16x2 (RNE), 1 instr for 2 values.
__device__ __forceinline__ unsigned cvtpk(float lo, float hi){
  unsigned r;
  asm("v_cvt_pk_bf16_f32 %0, %1, %2" : "=v"(r) : "v"(lo), "v"(hi));
  return r;
}

// Stage [R rows][32 bf16] bf16-global -> swizzled LDS via global_load_lds.
// 256-thread variant.
template<int R>
__device__ __forceinline__ void stage_glds(const unsigned short* gp, int ld, char* lds){
  const int tid = threadIdx.x;
  const int wid = tid >> 6;
#pragma unroll
  for (int q = 0; q < R/64; ++q){
    const int slot = q*256 + tid;            // = r*4 + unit
    const int r = slot >> 2, gi = slot & 3;
    const int u = gi ^ swz4(r);
    const unsigned short* ga = gp + r*ld + u*8;
    char* lb = lds + (q*256 + wid*64)*16;    // wave-uniform LDS base
    __builtin_amdgcn_global_load_lds(
        (__attribute__((address_space(1))) void*)ga,
        (__attribute__((address_space(3))) void*)lb, 16, 0, 0);
  }
}

// 512-thread variant (one 16B DMA per thread covers 128 rows).
template<int R>
__device__ __forceinline__ void stage_glds512(const unsigned short* gp, int ld, char* lds){
  const int tid = threadIdx.x;
  const int wid = tid >> 6;
#pragma unroll
  for (int q = 0; q < R/128; ++q){
    const int slot = q*512 + tid;            // = r*4 + unit
    const int r = slot >> 2, gi = slot & 3;
    const int u = gi ^ swz4(r);
    const unsigned short* ga = gp + r*ld + u*8;
    char* lb = lds + (q*512 + wid*64)*16;    // wave-uniform LDS base
    __builtin_amdgcn_global_load_lds(
        (__attribute__((address_space(1))) void*)ga,
        (__attribute__((address_space(3))) void*)lb, 16, 0, 0);
  }
}

__device__ __forceinline__ s16x8 ldsfrag(const char* lds, int r, int g){
  return *(const s16x8*)(lds + r*64 + ((g ^ swz4(r)) << 4));
}

// ---------------------------------------------------------------------------
// K0w: W fp32 -> bf16.
// ---------------------------------------------------------------------------
__global__ __launch_bounds__(256) void k0_w(
    const float* __restrict__ w, unsigned short* __restrict__ wb)
{
  const int i = blockIdx.x*256 + threadIdx.x;   // 16384 float4s
  float4 v = *(const float4*)(w + (size_t)i*4);
  uint2 h = {cvtpk(v.x, v.y), cvtpk(v.z, v.w)};
  *(uint2*)(wb + (size_t)i*4) = h;
}

// ---------------------------------------------------------------------------
// K1: qk = elu(W.x + b)+1.  MFMA GEMM M=256(o) x BN=64(n) x K=256(c).
// v2: 512 threads / 8 waves (r15 counters: occ 24%, 4-wave blocks with deep
// serial phases — halve per-thread phase depth, double resident waves; same
// proven r15 math/rounding, so outputs are bit-identical).
// Wave o-split 8 (M=32/wave, acc[2][4]). Waves 0-3 -> q half qt[b][n][d];
// waves 4-7 -> k half kbuf[b][d][n].
// ---------------------------------------------------------------------------
__global__ __launch_bounds__(512) void k1_qk(
    const float* __restrict__ x, const unsigned short* __restrict__ wb,
    const float* __restrict__ bias,
    unsigned short* __restrict__ kbuf, unsigned short* __restrict__ qt)
{
  __shared__ __align__(16) char Al[256*64];  // [256 o][32 c] bf16, swizzled
  __shared__ __align__(16) char Bl[64*64];   // [64 n][32 c]  bf16, swizzled
  const int tid = threadIdx.x, lane = tid & 63, wid = tid >> 6;
  const int n0 = blockIdx.x * 64;
  const int b  = blockIdx.y;
  const float* xb = x + (size_t)b*C_*N_;
  const int wo = wid*32;
  f32x4 acc[2][4] = {};
  const int cc = tid >> 4;            // 0..31 (c within K-step)
  const int nn = (tid & 15)*4;        // 0..60 (n within tile)

  for (int k0 = 0; k0 < C_; k0 += 32){
    // B tile load (x fp32, coalesced): issue BEFORE barrier to overlap MFMA
    float4 xv = *(const float4*)(xb + (size_t)(k0 + cc)*N_ + n0 + nn);
    __syncthreads();               // previous iteration's LDS reads done
    stage_glds512<256>(wb + k0, C_, Al);
    // transpose scatter: Bl[n][c] bf16, swz4 row swizzle (r2-proven)
    {
      const float vv[4] = {xv.x, xv.y, xv.z, xv.w};
#pragma unroll
      for (int i = 0; i < 4; ++i){
        const int r = nn + i;
        *(unsigned short*)(Bl + r*64 + ((cc*2) ^ (swz4(r) << 4))) = f2bf(vv[i]);
      }
    }
    __syncthreads();               // DMA + scatter visible
    s16x8 af[2], bv4[4];
#pragma unroll
    for (int m = 0; m < 2; ++m)  af[m]  = ldsfrag(Al, wo + m*16 + (lane & 15), lane >> 4);
#pragma unroll
    for (int nf = 0; nf < 4; ++nf) bv4[nf] = ldsfrag(Bl, nf*16 + (lane & 15), lane >> 4);
#pragma unroll
    for (int m = 0; m < 2; ++m)
#pragma unroll
      for (int nf = 0; nf < 4; ++nf)
        acc[m][nf] = __builtin_amdgcn_mfma_f32_16x16x32_bf16(af[m], bv4[nf], acc[m][nf], 0, 0, 0);
  }

  const int col = lane & 15, rg = lane >> 4;
  if (wid < 4){
    // q half -> qt[b][n][d]
#pragma unroll
    for (int m = 0; m < 2; ++m){
      const int db = wo + m*16 + rg*4;
      const float b0 = bias[db], b1 = bias[db+1], b2 = bias[db+2], b3 = bias[db+3];
#pragma unroll
      for (int nf = 0; nf < 4; ++nf){
        const int n = n0 + nf*16 + col;
        f32x4 a = acc[m][nf];
        uint2 hv = {cvtpk(elu1(a[0]+b0), elu1(a[1]+b1)),
                    cvtpk(elu1(a[2]+b2), elu1(a[3]+b3))};
        *(uint2*)(qt + ((size_t)b*N_ + n)*D_ + db) = hv;
      }
    }
  } else {
    // k half -> kbuf[b][d][n]
#pragma unroll
    for (int m = 0; m < 2; ++m)
#pragma unroll
      for (int j = 0; j < 4; ++j){
        const int d = wo - 128 + m*16 + rg*4 + j;
        const float bb = bias[128 + d];
#pragma unroll
        for (int nf = 0; nf < 4; ++nf){
          const int n = n0 + nf*16 + col;
          kbuf[((size_t)b*D_ + d)*N_ + n] = f2bf(elu1(acc[m][nf][j] + bb));
        }
      }
  }
}

// ---------------------------------------------------------------------------
// K2: kv partials = sum_n k[d][n]*x[c][n] over K-split. M=128(d) x BN=256(c)
// x K=448(n). 512 threads / 8 waves. Partials stored [c][d]. Fuses kmean.
// (EXACT round-7/15 proven version.)
// ---------------------------------------------------------------------------
__global__ __launch_bounds__(512) void k2_kv(
    const unsigned short* __restrict__ kbuf, const float* __restrict__ x,
    unsigned short* __restrict__ kvp, float* __restrict__ kmp)
{
  __shared__ __align__(16) char Al[128*64];  // [128 d][32 n]
  __shared__ __align__(16) char Bl[256*64];  // [256 c][32 n]
  const int tid = threadIdx.x, lane = tid & 63, wid = tid >> 6;  // 8 waves
  const int ks = blockIdx.x;
  const int b  = blockIdx.y;
  const unsigned short* kb = kbuf + (size_t)b*D_*N_ + ks*KRANGE;
  const float* xb = x + (size_t)b*C_*N_ + ks*KRANGE;
  const int wd = (wid >> 2)*64, wc = (wid & 3)*64;
  f32x4 acc[4][4] = {};
  float kms = 0.f;
  const int sr = tid >> 2, sg = tid & 3;     // staging/kms row & unit

  for (int t = 0; t < KRANGE/32; ++t){
    __syncthreads();
    // A: 128 rows x 4 units = 512 slots, one global_load_lds per thread
    {
      const int u = sg ^ swz4(sr);
      const unsigned short* ga = kb + (size_t)sr*N_ + t*32 + u*8;
      char* lb = Al + (wid*64)*16;           // wave-uniform base; unit = tid
      __builtin_amdgcn_global_load_lds(
          (__attribute__((address_space(1))) void*)ga,
          (__attribute__((address_space(3))) void*)lb, 16, 0, 0);
    }
    // B: x[c][n] fp32 -> bf16 (cvt_pk); 256 rows x 32 n, 16 elems/thread
#pragma unroll
    for (int q = 0; q < 4; ++q){
      int idx = q*512 + tid;                 // 0..2047
      int cc = idx >> 3, n4 = (idx & 7)*4;
      float4 v = *(const float4*)(xb + (size_t)cc*N_ + t*32 + n4);
      uint2 h = {cvtpk(v.x, v.y), cvtpk(v.z, v.w)};
      *(uint2*)(Bl + cc*64 + ((n4*2) ^ (swz4(cc) << 4))) = h;
    }
    __syncthreads();
    s16x8 af[4], bv[4];
#pragma unroll
    for (int m = 0; m < 4; ++m)  af[m] = ldsfrag(Al, wd + m*16 + (lane & 15), lane >> 4);
#pragma unroll
    for (int cf = 0; cf < 4; ++cf) bv[cf] = ldsfrag(Bl, wc + cf*16 + (lane & 15), lane >> 4);
#pragma unroll
    for (int m = 0; m < 4; ++m)
#pragma unroll
      for (int cf = 0; cf < 4; ++cf)
        acc[m][cf] = __builtin_amdgcn_mfma_f32_16x16x32_bf16(af[m], bv[cf], acc[m][cf], 0, 0, 0);
    // kmean partial: thread (sr, sg) sums unit sg of k-row sr (8 bf16)
    {
      uint2 u = *(const uint2*)(Al + sr*64 + ((sg ^ swz4(sr)) << 4));
      uint2 u2 = *(const uint2*)(Al + sr*64 + ((sg ^ swz4(sr)) << 4) + 8);
      const unsigned ua[4] = {u.x, u.y, u2.x, u2.y};
#pragma unroll
      for (int i = 0; i < 4; ++i){
        kms += bf2f((unsigned short)(ua[i] & 0xffffu));
        kms += bf2f((unsigned short)(ua[i] >> 16));
      }
    }
  }

  kms += __shfl_xor(kms, 1);
  kms += __shfl_xor(kms, 2);
  if ((tid & 3) == 0) kmp[((size_t)b*KSPLIT + ks)*D_ + sr] = kms;

  const int col = lane & 15, rg = lane >> 4;
#pragma unroll
  for (int m = 0; m < 4; ++m){
    const int d0 = wd + m*16 + rg*4;
#pragma unroll
    for (int cf = 0; cf < 4; ++cf){
      const int c = wc + cf*16 + col;
      ushort4 hv = {f2bf(acc[m][cf][0]), f2bf(acc[m][cf][1]),
                    f2bf(acc[m][cf][2]), f2bf(acc[m][cf][3])};
      *(ushort4*)(kvp + (((size_t)b*KSPLIT + ks)*C_ + c)*D_ + d0) = hv;
    }
  }
}

// ---------------------------------------------------------------------------
// KR: kvt[b][c][d] = (1/N) * sum_ks kvp[b][ks][c][d]; km[b][d] from kmp.
// (EXACT round-7 version — proven.)
// ---------------------------------------------------------------------------
__global__ __launch_bounds__(256) void kr_reduce(
    const unsigned short* __restrict__ kvp, const float* __restrict__ kmp,
    unsigned short* __restrict__ kvt, float* __restrict__ km)
{
  const int tid = threadIdx.x;
  const int bx = blockIdx.x, b = blockIdx.y;
  const float sc = 1.0f/(float)N_;
#pragma unroll
  for (int it = 0; it < 2; ++it){
    const int idx = (bx*2 + it)*256 + tid;      // 0..4095
    const int c = idx >> 4, dq = (idx & 15)*8;
    float s[8] = {};
    for (int ks = 0; ks < KSPLIT; ++ks){
      u16x8 v = *(const u16x8*)(kvp + (((size_t)b*KSPLIT + ks)*C_ + c)*D_ + dq);
#pragma unroll
      for (int i = 0; i < 8; ++i) s[i] += bf2f(v[i]);
    }
    u16x8 h;
#pragma unroll
    for (int i = 0; i < 8; ++i) h[i] = f2bf(s[i]*sc);
    *(u16x8*)(kvt + ((size_t)b*C_ + c)*D_ + dq) = h;
  }
  if (bx == 0 && tid < D_){
    float s = 0.f;
    for (int ks = 0; ks < KSPLIT; ++ks) s += kmp[((size_t)b*KSPLIT + ks)*D_ + tid];
    km[b*D_ + tid] = s*sc;
  }
}

// ---------------------------------------------------------------------------
// K3: attn[c][n] = (sum_d kvt[c][d]*qt[n][d]) / (q.km + 1e-6), bf16 out.
// (EXACT round-7 version — proven.)
// ---------------------------------------------------------------------------
__global__ __launch_bounds__(256) void k3_attn(
    const unsigned short* __restrict__ qt, const unsigned short* __restrict__ kvt,
    const float* __restrict__ km, unsigned short* __restrict__ attn)
{
  __shared__ __align__(16) char SM[256*64 + 64*64];  // 20KB
  char* Al = SM;                                 // [256 c][32 d] (16KB)
  char* Bl = SM + 256*64;                        // [64 n][32 d]  (4KB)
  unsigned short* P = (unsigned short*)SM;       // [128][72] bf16 (18KB overlay)
  __shared__ float kms[128];
  __shared__ float dens[64];
  const int tid = threadIdx.x, lane = tid & 63, wid = tid >> 6;
  const int n0 = blockIdx.x * 64;
  const int b  = blockIdx.y;
  if (tid < 128) kms[tid] = km[b*D_ + tid];
  const unsigned short* kvb = kvt + (size_t)b*C_*D_;
  const unsigned short* qtb = qt + ((size_t)b*N_ + n0)*D_;
  const int wc = wid*64;
  f32x4 acc[4][4] = {};
  float den = 0.f;

  for (int k0 = 0; k0 < D_; k0 += 32){
    __syncthreads();
    stage_glds<256>(kvb + k0, D_, Al);
    stage_glds<64>(qtb + k0, D_, Bl);
    __syncthreads();
    s16x8 af[4], bv4[4];
#pragma unroll
    for (int m = 0; m < 4; ++m)  af[m]  = ldsfrag(Al, wc + m*16 + (lane & 15), lane >> 4);
#pragma unroll
    for (int nf = 0; nf < 4; ++nf) bv4[nf] = ldsfrag(Bl, nf*16 + (lane & 15), lane >> 4);
#pragma unroll
    for (int m = 0; m < 4; ++m)
#pragma unroll
      for (int nf = 0; nf < 4; ++nf)
        acc[m][nf] = __builtin_amdgcn_mfma_f32_16x16x32_bf16(af[m], bv4[nf], acc[m][nf], 0, 0, 0);
    {
      const int nr = tid >> 2, g = tid & 3;
      uint4 u = *(const uint4*)(Bl + nr*64 + ((g ^ swz4(nr)) << 4));
      const float* kp = kms + k0 + g*8;
      const unsigned ua[4] = {u.x, u.y, u.z, u.w};
#pragma unroll
      for (int i = 0; i < 4; ++i){
        den += bf2f((unsigned short)(ua[i] & 0xffffu)) * kp[i*2];
        den += bf2f((unsigned short)(ua[i] >> 16))     * kp[i*2 + 1];
      }
    }
  }
  den += __shfl_xor(den, 1);
  den += __shfl_xor(den, 2);
  if ((tid & 3) == 0) dens[tid >> 2] = den;
  __syncthreads();   // GEMM LDS reads done + dens visible

  const int col = lane & 15, rg = lane >> 4;
  float rdv[4];
#pragma unroll
  for (int nf = 0; nf < 4; ++nf)
    rdv[nf] = 1.0f / (dens[nf*16 + col] + 1e-6f);

#pragma unroll
  for (int h = 0; h < 2; ++h){
    if ((wid >> 1) == h){
      const int lc = wc - h*128;   // 0 or 64
#pragma unroll
      for (int m = 0; m < 4; ++m)
#pragma unroll
        for (int nf = 0; nf < 4; ++nf)
#pragma unroll
          for (int j = 0; j < 4; ++j)
            P[(lc + m*16 + rg*4 + j)*72 + (nf*16 + col)] = f2bf(acc[m][nf][j] * rdv[nf]);
    }
    __syncthreads();
#pragma unroll
    for (int p = 0; p < 4; ++p){
      const int c = (tid >> 3) + p*32, ch = tid & 7;
      u16x8 v = *(const u16x8*)(P + c*72 + ch*8);
      *(u16x8*)(attn + ((size_t)b*C_ + h*128 + c)*N_ + n0 + ch*8) = v;
    }
    __syncthreads();
  }
}

// ---------------------------------------------------------------------------
// K4: out = attn + depthwise3x3(x) + pe_b. Plane per block, 4-wide along w,
// zero-padded top/bottom LDS rows. x fp32 (EXACT round-7 proven path).
// ---------------------------------------------------------------------------
__global__ __launch_bounds__(256) void k4_pe(
    const float* __restrict__ x, const unsigned short* __restrict__ attn,
    const float* __restrict__ pw, const float* __restrict__ pb,
    float* __restrict__ out)
{
  __shared__ float xs_raw[58*56 + 8];
  float* xs = xs_raw + 4;          // slack so xs[-1] stays in-bounds
  const int tid = threadIdx.x;
  const int ch = blockIdx.x, b = blockIdx.y;
  if (tid < 14)      ((float4*)xs)[tid] = (float4){0.f,0.f,0.f,0.f};        // pad row 0
  else if (tid < 28) ((float4*)xs)[784 + tid] = (float4){0.f,0.f,0.f,0.f};  // pad row 57
  const float* xp = x + ((size_t)b*C_ + ch)*N_;
  for (int i = tid; i < 784; i += 256)
    ((float4*)xs)[14 + i] = ((const float4*)xp)[i];
  const float* wp = pw + ch*9;
  float wgt[9];
#pragma unroll
  for (int i = 0; i < 9; ++i) wgt[i] = wp[i];
  const float bias = pb[ch];
  __syncthreads();
  const unsigned short* ap = attn + ((size_t)b*C_ + ch)*N_;
  float* op = out + ((size_t)b*C_ + ch)*N_;
  for (int u = tid; u < 784; u += 256) {
    const int row = u / 14, g = u - row*14;     // output row, float4 group
    float o0 = bias, o1 = bias, o2 = bias, o3 = bias;
#pragma unroll
    for (int rr = 0; rr < 3; ++rr){
      const float* rp = xs + (row + rr)*56 + g*4;   // padded rows row..row+2
      float4 cv = *(const float4*)rp;
      float lf = (g > 0)  ? rp[-1] : 0.f;
      float rt = (g < 13) ? rp[4]  : 0.f;
      const float wl = wgt[rr*3], wc_ = wgt[rr*3+1], wr = wgt[rr*3+2];
      o0 += wl*lf   + wc_*cv.x + wr*cv.y;
      o1 += wl*cv.x + wc_*cv.y + wr*cv.z;
      o2 += wl*cv.y + wc_*cv.z + wr*cv.w;
      o3 += wl*cv.z + wc_*cv.w + wr*rt;
    }
    ushort4 av = *(const ushort4*)(ap + u*4);
    float4 ov = {o0 + bf2f(av.x), o1 + bf2f(av.y), o2 + bf2f(av.z), o3 + bf2f(av.w)};
    *(float4*)(op + u*4) = ov;
  }
}

extern "C" void kernel_launch(void* const* d_in, const int* in_sizes, int n_in,
                              void* d_out, int out_size, void* d_ws, size_t ws_size,
                              hipStream_t stream) {
  (void)in_sizes; (void)n_in; (void)out_size; (void)ws_size;
  const float* x   = (const float*)d_in[0];
  const float* qkw = (const float*)d_in[1];
  const float* qkb = (const float*)d_in[2];
  const float* pew = (const float*)d_in[3];
  const float* peb = (const float*)d_in[4];
  float* out = (float*)d_out;

  // ws layout (104.9 MB footprint, proven since round 7). slot0 (51.4 MB)
  // hosts kvp+kmp (k2->kr) then attn (k3->k4). kvt slot hosts wb then kvt.
  unsigned short* slot0 = (unsigned short*)d_ws;                // 51.4 MB scratch
  unsigned short* kbuf = slot0 + (size_t)B_*N_*C_;              // [B][128][N] bf16
  unsigned short* qt   = kbuf + (size_t)B_*D_*N_;               // [B][N][128] bf16
  unsigned short* kvt  = qt   + (size_t)B_*N_*D_;               // [B][256][128] bf16
  float* km  = (float*)(kvt + (size_t)B_*C_*D_);                // [B][128] f32
  unsigned short* wb   = kvt;                                   // [256][256] bf16 (alias)
  unsigned short* kvp  = slot0;                                 // [B][7][256][128] bf16 (alias)
  float* kmp = (float*)(kvp + (size_t)B_*KSPLIT*C_*D_);         // [B][7][128] f32 (in slot0)
  unsigned short* attn = slot0;                                 // [B][256][N] bf16 (alias)

  k0_w     <<<dim3(64),          256, 0, stream>>>(qkw, wb);
  k1_qk    <<<dim3(N_/64, B_),   512, 0, stream>>>(x, wb, qkb, kbuf, qt);
  k2_kv    <<<dim3(KSPLIT, B_),  512, 0, stream>>>(kbuf, x, kvp, kmp);
  kr_reduce<<<dim3(8, B_),       256, 0, stream>>>(kvp, kmp, kvt, km);
  k3_attn  <<<dim3(N_/64, B_),   256, 0, stream>>>(qt, kvt, km, attn);
  k4_pe    <<<dim3(C_, B_),      256, 0, stream>>>(x, attn, pew, peb, out);
}